// Round 4
// baseline (576.416 us; speedup 1.0000x reference)
//
#include <hip/hip_runtime.h>
#include <hip/hip_bf16.h>

typedef __attribute__((ext_vector_type(8))) short short8;
typedef __attribute__((ext_vector_type(4))) float f32x4;
typedef __attribute__((ext_vector_type(8))) unsigned short ushortv8;
typedef ushortv8 ushortv8_a __attribute__((may_alias));

#define S_LEN 2048
#define DMODEL 2048
#define N_HEADS 16
#define HEAD_DIM 128
#define SOFTCAP_F 50.0f
#define F32_TAG 0x3F800000u

__device__ __forceinline__ float bf2f(__hip_bfloat16 b) { return __bfloat162float(b); }
__device__ __forceinline__ __hip_bfloat16 f2bf(float f) { return __float2bfloat16(f); }

__device__ __forceinline__ unsigned short bf_bits(__hip_bfloat16 b) {
    union { __hip_bfloat16 b; unsigned short u; } x; x.b = b; return x.u;
}

// Read element i of an input buffer whose dtype is decided at runtime (uniform branch).
__device__ __forceinline__ float in_elem(const void* p, size_t i, bool is_f32) {
    return is_f32 ? ((const float*)p)[i] : bf2f(((const __hip_bfloat16*)p)[i]);
}

// Output-type-polymorphic store for the GEMM epilogue.
__device__ __forceinline__ void st_out(float* C, size_t i, float v) { C[i] = v; }
__device__ __forceinline__ void st_out(__hip_bfloat16* C, size_t i, float v) { C[i] = f2bf(v); }

__device__ __forceinline__ float tanh_fast(float x) {
    float e = __expf(2.0f * x);
    return 1.0f - 2.0f / (e + 1.0f);
}

#if __has_builtin(__builtin_amdgcn_global_load_lds)
#define HAVE_ASYNC_LDS 1
#else
#define HAVE_ASYNC_LDS 0
#endif

// Stage 16B per lane into LDS. ldsbase must be wave-uniform; HW scatters lane i at base + 16*i.
__device__ __forceinline__ void stage16(const __hip_bfloat16* g, __hip_bfloat16* ldsbase, int lane) {
#if HAVE_ASYNC_LDS
    __builtin_amdgcn_global_load_lds(
        (const __attribute__((address_space(1))) unsigned int*)g,
        (__attribute__((address_space(3))) unsigned int*)ldsbase,
        16, 0, 0);
#else
    *(short8*)((char*)ldsbase + lane * 16) = *(const short8*)g;
#endif
}

// ---------------- x -> bf16 (copy or downconvert), n = S*DM ----------------
__global__ __launch_bounds__(256) void convert_x(const void* __restrict__ in,
                                                 __hip_bfloat16* __restrict__ out,
                                                 const unsigned int* __restrict__ probe) {
    const bool is_f32 = (*probe == F32_TAG);
    size_t i = (size_t)blockIdx.x * 256 + threadIdx.x;
    out[i] = f2bf(in_elem(in, i, is_f32));
}

// ---------------- transpose 2048x2048 (runtime input dtype) -> bf16 ----------------
__global__ __launch_bounds__(256) void transpose_any(const void* __restrict__ in,
                                                     __hip_bfloat16* __restrict__ out,
                                                     const unsigned int* __restrict__ probe) {
    const bool is_f32 = (*probe == F32_TAG);
    __shared__ __hip_bfloat16 tile[32][33];
    int bx = blockIdx.x * 32;
    int by = blockIdx.y * 32;
    int tx = threadIdx.x;      // 0..31
    int ty = threadIdx.y;      // 0..7
    for (int i = ty; i < 32; i += 8)
        tile[i][tx] = f2bf(in_elem(in, (size_t)(by + i) * DMODEL + bx + tx, is_f32));
    __syncthreads();
    for (int i = ty; i < 32; i += 8)
        out[(size_t)(bx + i) * DMODEL + by + tx] = tile[tx][i];
}

// ---------------- transpose 2048x2048 bf16 (for V) ----------------
__global__ __launch_bounds__(256) void transpose_bf16(const __hip_bfloat16* __restrict__ in,
                                                      __hip_bfloat16* __restrict__ out) {
    __shared__ __hip_bfloat16 tile[32][33];
    int bx = blockIdx.x * 32;
    int by = blockIdx.y * 32;
    int tx = threadIdx.x;
    int ty = threadIdx.y;
    for (int i = ty; i < 32; i += 8)
        tile[i][tx] = in[(size_t)(by + i) * DMODEL + bx + tx];
    __syncthreads();
    for (int i = ty; i < 32; i += 8)
        out[(size_t)(bx + i) * DMODEL + by + tx] = tile[tx][i];
}

// ---------------- bf16 GEMM: C[M][N] = A[M][K] * Bt[N][K]^T (m97 pattern) ----------------
// OutT selects the epilogue store type: bf16 for intermediates, float for the final output.
template <typename OutT>
__global__ __launch_bounds__(256) void gemm_bt(const __hip_bfloat16* __restrict__ A,
                                               const __hip_bfloat16* __restrict__ Bt,
                                               OutT* __restrict__ C,
                                               int M, int N, int K) {
    __shared__ alignas(16) __hip_bfloat16 As[128 * 32];
    __shared__ alignas(16) __hip_bfloat16 Bs[128 * 32];
    const int tid = threadIdx.x;
    const int wave = tid >> 6;
    const int lane = tid & 63;
    const int lane15 = lane & 15;
    const int quad = lane >> 4;
    const int m0 = blockIdx.y * 128;
    const int n0 = blockIdx.x * 128;
    const int wm = (wave >> 1) * 64;
    const int wn = (wave & 1) * 64;

    f32x4 acc[4][4];
    for (int i = 0; i < 4; ++i)
        for (int j = 0; j < 4; ++j)
            acc[i][j] = {0.f, 0.f, 0.f, 0.f};

    const int rA = lane >> 2;
    const int cA = (lane & 3) * 8;

    for (int k0 = 0; k0 < K; k0 += 32) {
        __syncthreads();
        for (int c = 0; c < 4; ++c) {
            int chunk = wave * 4 + c;
            if (chunk < 8) {
                int r = chunk * 16 + rA;
                stage16(A + (size_t)(m0 + r) * K + k0 + cA, As + chunk * 512, lane);
            } else {
                int r = (chunk - 8) * 16 + rA;
                stage16(Bt + (size_t)(n0 + r) * K + k0 + cA, Bs + (chunk - 8) * 512, lane);
            }
        }
#if HAVE_ASYNC_LDS
        asm volatile("s_waitcnt vmcnt(0)" ::: "memory");
#endif
        __syncthreads();

        short8 af[4], bfr[4];
        for (int mt = 0; mt < 4; ++mt)
            af[mt] = *(const short8*)(As + (wm + mt * 16 + lane15) * 32 + quad * 8);
        for (int nt = 0; nt < 4; ++nt)
            bfr[nt] = *(const short8*)(Bs + (wn + nt * 16 + lane15) * 32 + quad * 8);
        for (int mt = 0; mt < 4; ++mt)
            for (int nt = 0; nt < 4; ++nt)
                acc[mt][nt] = __builtin_amdgcn_mfma_f32_16x16x32_bf16(af[mt], bfr[nt], acc[mt][nt], 0, 0, 0);
    }

    for (int mt = 0; mt < 4; ++mt)
        for (int nt = 0; nt < 4; ++nt)
            for (int i = 0; i < 4; ++i) {
                int row = m0 + wm + mt * 16 + quad * 4 + i;
                int col = n0 + wn + nt * 16 + lane15;
                st_out(C, (size_t)row * N + col, acc[mt][nt][i]);
            }
}

// ---------------- RoPE (in-place on Q and K, interleaved pairs) ----------------
__global__ __launch_bounds__(256) void rope_kernel(__hip_bfloat16* __restrict__ Q,
                                                   __hip_bfloat16* __restrict__ Kb,
                                                   const void* __restrict__ fc,
                                                   const void* __restrict__ fs,
                                                   const unsigned int* __restrict__ probe) {
    const bool is_f32 = (*probe == F32_TAG);
    int idx = blockIdx.x * 256 + threadIdx.x;  // 0 .. S*DM/2-1
    int s = idx >> 10;
    int p = idx & 1023;
    int j = p & 63;
    float c = in_elem(fc, (size_t)s * 64 + j, is_f32);
    float sn = in_elem(fs, (size_t)s * 64 + j, is_f32);
    __hip_bfloat16* base = blockIdx.y ? Kb : Q;
    size_t off = (size_t)s * DMODEL + 2 * p;
    float e = bf2f(base[off]);
    float o = bf2f(base[off + 1]);
    base[off]     = f2bf(e * c - o * sn);
    base[off + 1] = f2bf(e * sn + o * c);
}

// ---------------- flash attention ----------------
// Block = 4 waves sharing ONE q-tile (uniform trip count -> __syncthreads legal),
// each wave a different head. Q,K row-major [S][DM]; V from Vt [DM][S].
__global__ __launch_bounds__(256) void flash_attn(const __hip_bfloat16* __restrict__ Q,
                                                  const __hip_bfloat16* __restrict__ Kb,
                                                  const __hip_bfloat16* __restrict__ Vt,
                                                  __hip_bfloat16* __restrict__ O) {
    __shared__ alignas(16) unsigned short Pl[4][16][40];
    const int wave = threadIdx.x >> 6;
    const int lane = threadIdx.x & 63;
    const int lane15 = lane & 15;
    const int quad = lane >> 4;
    const int bx = blockIdx.x;              // 0..511
    const int qt = 127 - (bx >> 2);         // big tiles first
    const int head = (bx & 3) * 4 + wave;
    const int q0 = qt * 16;
    const float scale = 0.08838834764831845f;  // 1/sqrt(128)

    const __hip_bfloat16* Qh = Q + (size_t)q0 * DMODEL + head * HEAD_DIM;
    short8 qf[4];
    for (int kk = 0; kk < 4; ++kk)
        qf[kk] = *(const short8*)(Qh + (size_t)lane15 * DMODEL + kk * 32 + quad * 8);

    f32x4 acc[8];
    for (int i = 0; i < 8; ++i) acc[i] = {0.f, 0.f, 0.f, 0.f};
    float m_i[4], l_i[4];
    for (int i = 0; i < 4; ++i) { m_i[i] = -1e30f; l_i[i] = 0.f; }

    const int nkt = (q0 + 16 + 31) >> 5;
    for (int kt = 0; kt < nkt; ++kt) {
        int kb = kt * 32;
        f32x4 sc[2];
        sc[0] = {0.f, 0.f, 0.f, 0.f};
        sc[1] = {0.f, 0.f, 0.f, 0.f};
        for (int c = 0; c < 2; ++c) {
            const __hip_bfloat16* Kp = Kb + (size_t)(kb + c * 16 + lane15) * DMODEL + head * HEAD_DIM;
            for (int kk = 0; kk < 4; ++kk) {
                short8 kf = *(const short8*)(Kp + kk * 32 + quad * 8);
                sc[c] = __builtin_amdgcn_mfma_f32_16x16x32_bf16(qf[kk], kf, sc[c], 0, 0, 0);
            }
        }
        int key0 = kb + lane15;
        int key1 = kb + 16 + lane15;
        __syncthreads();  // previous P reads done before overwriting Pl
        for (int i = 0; i < 4; ++i) {
            int q = q0 + quad * 4 + i;
            float v0 = sc[0][i] * scale;
            float v1 = sc[1][i] * scale;
            v0 = SOFTCAP_F * tanh_fast(v0 * (1.0f / SOFTCAP_F));
            v1 = SOFTCAP_F * tanh_fast(v1 * (1.0f / SOFTCAP_F));
            if (key0 > q) v0 = -1e30f;
            if (key1 > q) v1 = -1e30f;
            float mx = fmaxf(v0, v1);
            mx = fmaxf(mx, __shfl_xor(mx, 1, 64));
            mx = fmaxf(mx, __shfl_xor(mx, 2, 64));
            mx = fmaxf(mx, __shfl_xor(mx, 4, 64));
            mx = fmaxf(mx, __shfl_xor(mx, 8, 64));
            float mnew = fmaxf(m_i[i], mx);
            float alpha = __expf(m_i[i] - mnew);
            float p0 = __expf(v0 - mnew);
            float p1 = __expf(v1 - mnew);
            // round P to bf16 BEFORE summing l so l matches the P used in PV
            __hip_bfloat16 b0 = f2bf(p0), b1 = f2bf(p1);
            float rs = bf2f(b0) + bf2f(b1);
            rs += __shfl_xor(rs, 1, 64);
            rs += __shfl_xor(rs, 2, 64);
            rs += __shfl_xor(rs, 4, 64);
            rs += __shfl_xor(rs, 8, 64);
            l_i[i] = l_i[i] * alpha + rs;
            m_i[i] = mnew;
            for (int nt = 0; nt < 8; ++nt) acc[nt][i] *= alpha;
            Pl[wave][quad * 4 + i][lane15] = bf_bits(b0);
            Pl[wave][quad * 4 + i][16 + lane15] = bf_bits(b1);
        }
        __syncthreads();  // P stores drained
        ushortv8_a pv = *(const ushortv8_a*)(&Pl[wave][lane15][quad * 8]);
        asm volatile("" ::: "memory");
        short8 pf;
        __builtin_memcpy(&pf, &pv, 16);
        for (int nt = 0; nt < 8; ++nt) {
            const __hip_bfloat16* Vp = Vt + (size_t)(head * HEAD_DIM + nt * 16 + lane15) * S_LEN + kb + quad * 8;
            short8 vf = *(const short8*)Vp;
            acc[nt] = __builtin_amdgcn_mfma_f32_16x16x32_bf16(pf, vf, acc[nt], 0, 0, 0);
        }
    }

    for (int i = 0; i < 4; ++i) {
        int row = q0 + quad * 4 + i;
        float inv = 1.0f / l_i[i];
        for (int nt = 0; nt < 8; ++nt) {
            int col = head * HEAD_DIM + nt * 16 + lane15;
            O[(size_t)row * DMODEL + col] = f2bf(acc[nt][i] * inv);
        }
    }
}

extern "C" void kernel_launch(void* const* d_in, const int* in_sizes, int n_in,
                              void* d_out, int out_size, void* d_ws, size_t ws_size,
                              hipStream_t stream) {
    const void* x  = d_in[0];
    const void* wq = d_in[1];
    const void* wk = d_in[2];
    const void* wv = d_in[3];
    const void* wo = d_in[4];
    const void* fc = d_in[5];
    const void* fs = d_in[6];
    const unsigned int* probe = (const unsigned int*)d_in[5];  // fc[0] == 1.0
    float* out = (float*)d_out;  // reference output dtype is float32

    char* ws = (char*)d_ws;
    const size_t MB8 = (size_t)2048 * 2048 * sizeof(__hip_bfloat16);
    __hip_bfloat16* T0   = (__hip_bfloat16*)(ws + 0 * MB8);  // reusable weight-transpose slot
    __hip_bfloat16* Qb   = (__hip_bfloat16*)(ws + 1 * MB8);
    __hip_bfloat16* Kbuf = (__hip_bfloat16*)(ws + 2 * MB8);
    __hip_bfloat16* Vbuf = (__hip_bfloat16*)(ws + 3 * MB8);  // reused as attention output
    __hip_bfloat16* Vt   = (__hip_bfloat16*)(ws + 4 * MB8);
    __hip_bfloat16* x_bf = (__hip_bfloat16*)(ws + 5 * MB8);
    __hip_bfloat16* attn = Vbuf;

    dim3 tb(32, 8);
    dim3 tg(64, 64);
    dim3 gb(16, 16);

    convert_x<<<16384, 256, 0, stream>>>(x, x_bf, probe);

    transpose_any<<<tg, tb, 0, stream>>>(wq, T0, probe);
    gemm_bt<__hip_bfloat16><<<gb, 256, 0, stream>>>(x_bf, T0, Qb, 2048, 2048, 2048);

    transpose_any<<<tg, tb, 0, stream>>>(wk, T0, probe);
    gemm_bt<__hip_bfloat16><<<gb, 256, 0, stream>>>(x_bf, T0, Kbuf, 2048, 2048, 2048);

    transpose_any<<<tg, tb, 0, stream>>>(wv, T0, probe);
    gemm_bt<__hip_bfloat16><<<gb, 256, 0, stream>>>(x_bf, T0, Vbuf, 2048, 2048, 2048);

    rope_kernel<<<dim3(8192, 2), 256, 0, stream>>>(Qb, Kbuf, fc, fs, probe);
    transpose_bf16<<<tg, tb, 0, stream>>>(Vbuf, Vt);

    flash_attn<<<512, 256, 0, stream>>>(Qb, Kbuf, Vt, attn);

    transpose_any<<<tg, tb, 0, stream>>>(wo, T0, probe);
    gemm_bt<float><<<gb, 256, 0, stream>>>(attn, T0, out, 2048, 2048, 2048);
}

// Round 5
// 436.284 us; speedup vs baseline: 1.3212x; 1.3212x over previous
//
#include <hip/hip_runtime.h>
#include <hip/hip_bf16.h>

typedef __attribute__((ext_vector_type(8))) short short8;
typedef __attribute__((ext_vector_type(4))) float f32x4;
typedef __attribute__((ext_vector_type(4))) unsigned short ushort4v;
typedef __attribute__((ext_vector_type(8))) unsigned short ushortv8;
typedef ushortv8 ushortv8_a __attribute__((may_alias));

#define S_LEN 2048
#define DMODEL 2048
#define N_HEADS 16
#define HEAD_DIM 128

__device__ __forceinline__ float bf2f(__hip_bfloat16 b) { return __bfloat162float(b); }
__device__ __forceinline__ __hip_bfloat16 f2bf(float f) { return __float2bfloat16(f); }

__device__ __forceinline__ unsigned short bf_bits(__hip_bfloat16 b) {
    union { __hip_bfloat16 b; unsigned short u; } x; x.b = b; return x.u;
}

#if __has_builtin(__builtin_amdgcn_global_load_lds)
#define HAVE_ASYNC_LDS 1
#else
#define HAVE_ASYNC_LDS 0
#endif

// Stage 16B per lane into LDS. ldsbase must be wave-uniform; HW scatters lane i at base + 16*i.
__device__ __forceinline__ void stage16(const __hip_bfloat16* g, __hip_bfloat16* ldsbase, int lane) {
#if HAVE_ASYNC_LDS
    __builtin_amdgcn_global_load_lds(
        (const __attribute__((address_space(1))) unsigned int*)g,
        (__attribute__((address_space(3))) unsigned int*)ldsbase,
        16, 0, 0);
#else
    *(short8*)((char*)ldsbase + lane * 16) = *(const short8*)g;
#endif
}

// ---------------- x (f32) -> bf16 ----------------
__global__ __launch_bounds__(256) void convert_x(const float* __restrict__ in,
                                                 __hip_bfloat16* __restrict__ out) {
    size_t i = (size_t)blockIdx.x * 256 + threadIdx.x;
    out[i] = f2bf(in[i]);
}

// ---------------- transpose 2048x2048 f32 -> bf16 ----------------
__global__ __launch_bounds__(256) void transpose_f32(const float* __restrict__ in,
                                                     __hip_bfloat16* __restrict__ out) {
    __shared__ __hip_bfloat16 tile[32][33];
    int bx = blockIdx.x * 32;
    int by = blockIdx.y * 32;
    int tx = threadIdx.x;      // 0..31
    int ty = threadIdx.y;      // 0..7
    for (int i = ty; i < 32; i += 8)
        tile[i][tx] = f2bf(in[(size_t)(by + i) * DMODEL + bx + tx]);
    __syncthreads();
    for (int i = ty; i < 32; i += 8)
        out[(size_t)(bx + i) * DMODEL + by + tx] = tile[tx][i];
}

// ---------------- fused QKV GEMM ----------------
// grid (48,16): blockIdx.x>>4 selects {Q,K,V}. 128x128 tile, BK=32, m97 pattern.
// V blocks write their C tile TRANSPOSED (Vt[d][s]) with packed 4xbf16 stores.
__global__ __launch_bounds__(256) void gemm_qkv(const __hip_bfloat16* __restrict__ A,
                                                const __hip_bfloat16* __restrict__ Bq,
                                                const __hip_bfloat16* __restrict__ Bk,
                                                const __hip_bfloat16* __restrict__ Bv,
                                                __hip_bfloat16* __restrict__ Cq,
                                                __hip_bfloat16* __restrict__ Ck,
                                                __hip_bfloat16* __restrict__ Cvt) {
    __shared__ alignas(16) __hip_bfloat16 As[128 * 32];
    __shared__ alignas(16) __hip_bfloat16 Bs[128 * 32];
    const int which = blockIdx.x >> 4;
    const __hip_bfloat16* Bt = (which == 0) ? Bq : (which == 1) ? Bk : Bv;
    const int tid = threadIdx.x;
    const int wave = tid >> 6;
    const int lane = tid & 63;
    const int lane15 = lane & 15;
    const int quad = lane >> 4;
    const int m0 = blockIdx.y * 128;
    const int n0 = (blockIdx.x & 15) * 128;
    const int wm = (wave >> 1) * 64;
    const int wn = (wave & 1) * 64;

    f32x4 acc[4][4];
    for (int i = 0; i < 4; ++i)
        for (int j = 0; j < 4; ++j)
            acc[i][j] = {0.f, 0.f, 0.f, 0.f};

    const int rA = lane >> 2;
    const int cA = (lane & 3) * 8;

    for (int k0 = 0; k0 < DMODEL; k0 += 32) {
        __syncthreads();
        for (int c = 0; c < 4; ++c) {
            int chunk = wave * 4 + c;
            if (chunk < 8) {
                int r = chunk * 16 + rA;
                stage16(A + (size_t)(m0 + r) * DMODEL + k0 + cA, As + chunk * 512, lane);
            } else {
                int r = (chunk - 8) * 16 + rA;
                stage16(Bt + (size_t)(n0 + r) * DMODEL + k0 + cA, Bs + (chunk - 8) * 512, lane);
            }
        }
#if HAVE_ASYNC_LDS
        asm volatile("s_waitcnt vmcnt(0)" ::: "memory");
#endif
        __syncthreads();

        short8 af[4], bfr[4];
        for (int mt = 0; mt < 4; ++mt)
            af[mt] = *(const short8*)(As + (wm + mt * 16 + lane15) * 32 + quad * 8);
        for (int nt = 0; nt < 4; ++nt)
            bfr[nt] = *(const short8*)(Bs + (wn + nt * 16 + lane15) * 32 + quad * 8);
        for (int mt = 0; mt < 4; ++mt)
            for (int nt = 0; nt < 4; ++nt)
                acc[mt][nt] = __builtin_amdgcn_mfma_f32_16x16x32_bf16(af[mt], bfr[nt], acc[mt][nt], 0, 0, 0);
    }

    if (which < 2) {
        __hip_bfloat16* C = (which == 0) ? Cq : Ck;
        for (int mt = 0; mt < 4; ++mt)
            for (int nt = 0; nt < 4; ++nt)
                for (int i = 0; i < 4; ++i) {
                    int row = m0 + wm + mt * 16 + quad * 4 + i;
                    int col = n0 + wn + nt * 16 + lane15;
                    C[(size_t)row * DMODEL + col] = f2bf(acc[mt][nt][i]);
                }
    } else {
        // transposed store: Cvt[col][row], 4 consecutive rows packed per lane
        for (int mt = 0; mt < 4; ++mt) {
            int rowbase = m0 + wm + mt * 16 + quad * 4;
            for (int nt = 0; nt < 4; ++nt) {
                int col = n0 + wn + nt * 16 + lane15;
                ushort4v pk;
                pk.x = bf_bits(f2bf(acc[mt][nt][0]));
                pk.y = bf_bits(f2bf(acc[mt][nt][1]));
                pk.z = bf_bits(f2bf(acc[mt][nt][2]));
                pk.w = bf_bits(f2bf(acc[mt][nt][3]));
                *(ushort4v*)(Cvt + (size_t)col * S_LEN + rowbase) = pk;
            }
        }
    }
}

// ---------------- final GEMM: out(f32) = A * Bt^T ----------------
__global__ __launch_bounds__(256) void gemm_out(const __hip_bfloat16* __restrict__ A,
                                                const __hip_bfloat16* __restrict__ Bt,
                                                float* __restrict__ C) {
    __shared__ alignas(16) __hip_bfloat16 As[128 * 32];
    __shared__ alignas(16) __hip_bfloat16 Bs[128 * 32];
    const int tid = threadIdx.x;
    const int wave = tid >> 6;
    const int lane = tid & 63;
    const int lane15 = lane & 15;
    const int quad = lane >> 4;
    const int m0 = blockIdx.y * 128;
    const int n0 = blockIdx.x * 128;
    const int wm = (wave >> 1) * 64;
    const int wn = (wave & 1) * 64;

    f32x4 acc[4][4];
    for (int i = 0; i < 4; ++i)
        for (int j = 0; j < 4; ++j)
            acc[i][j] = {0.f, 0.f, 0.f, 0.f};

    const int rA = lane >> 2;
    const int cA = (lane & 3) * 8;

    for (int k0 = 0; k0 < DMODEL; k0 += 32) {
        __syncthreads();
        for (int c = 0; c < 4; ++c) {
            int chunk = wave * 4 + c;
            if (chunk < 8) {
                int r = chunk * 16 + rA;
                stage16(A + (size_t)(m0 + r) * DMODEL + k0 + cA, As + chunk * 512, lane);
            } else {
                int r = (chunk - 8) * 16 + rA;
                stage16(Bt + (size_t)(n0 + r) * DMODEL + k0 + cA, Bs + (chunk - 8) * 512, lane);
            }
        }
#if HAVE_ASYNC_LDS
        asm volatile("s_waitcnt vmcnt(0)" ::: "memory");
#endif
        __syncthreads();

        short8 af[4], bfr[4];
        for (int mt = 0; mt < 4; ++mt)
            af[mt] = *(const short8*)(As + (wm + mt * 16 + lane15) * 32 + quad * 8);
        for (int nt = 0; nt < 4; ++nt)
            bfr[nt] = *(const short8*)(Bs + (wn + nt * 16 + lane15) * 32 + quad * 8);
        for (int mt = 0; mt < 4; ++mt)
            for (int nt = 0; nt < 4; ++nt)
                acc[mt][nt] = __builtin_amdgcn_mfma_f32_16x16x32_bf16(af[mt], bfr[nt], acc[mt][nt], 0, 0, 0);
    }

    for (int mt = 0; mt < 4; ++mt)
        for (int nt = 0; nt < 4; ++nt)
            for (int i = 0; i < 4; ++i) {
                int row = m0 + wm + mt * 16 + quad * 4 + i;
                int col = n0 + wn + nt * 16 + lane15;
                C[(size_t)row * DMODEL + col] = acc[mt][nt][i];
            }
}

// ---------------- RoPE (in-place on Q and K) ----------------
__global__ __launch_bounds__(256) void rope_kernel(__hip_bfloat16* __restrict__ Q,
                                                   __hip_bfloat16* __restrict__ Kb,
                                                   const float* __restrict__ fc,
                                                   const float* __restrict__ fs) {
    int idx = blockIdx.x * 256 + threadIdx.x;  // 0 .. S*DM/2-1
    int s = idx >> 10;
    int p = idx & 1023;
    int j = p & 63;
    float c = fc[s * 64 + j];
    float sn = fs[s * 64 + j];
    __hip_bfloat16* base = blockIdx.y ? Kb : Q;
    size_t off = (size_t)s * DMODEL + 2 * p;
    float e = bf2f(base[off]);
    float o = bf2f(base[off + 1]);
    base[off]     = f2bf(e * c - o * sn);
    base[off + 1] = f2bf(e * sn + o * c);
}

// ---------------- flash attention (barrier-free, fixed-base softmax) ----------------
// Softcap bounds scores to [-50,50], so p = exp(s - 10) spans [e^-60, e^40]:
// always inside fp32 AND bf16 normal range -> no online max, no rescale needed.
// One wave per (head, 16-row q-tile); per-wave LDS region for the P layout flip.
__global__ __launch_bounds__(256) void flash_attn(const __hip_bfloat16* __restrict__ Q,
                                                  const __hip_bfloat16* __restrict__ Kb,
                                                  const __hip_bfloat16* __restrict__ Vt,
                                                  __hip_bfloat16* __restrict__ O) {
    __shared__ alignas(16) unsigned short Pl[4][16][40];
    const int wave = threadIdx.x >> 6;
    const int lane = threadIdx.x & 63;
    const int lane15 = lane & 15;
    const int quad = lane >> 4;
    const int bx = blockIdx.x;              // 0..511
    const int qt = 127 - (bx >> 2);         // big causal spans first
    const int head = (bx & 3) * 4 + wave;
    const int q0 = qt * 16;
    // scale/25 (feeds exp for tanh); capped = 40 - 100/(e2+1); p = exp(capped)
    const float K1 = 0.08838834764831845f * (1.0f / 25.0f);

    const __hip_bfloat16* Qh = Q + (size_t)q0 * DMODEL + head * HEAD_DIM;
    short8 qf[4];
    for (int kk = 0; kk < 4; ++kk)
        qf[kk] = *(const short8*)(Qh + (size_t)lane15 * DMODEL + kk * 32 + quad * 8);

    f32x4 acc[8];
    for (int i = 0; i < 8; ++i) acc[i] = {0.f, 0.f, 0.f, 0.f};
    float lpart[4] = {0.f, 0.f, 0.f, 0.f};

    const int nkt = (q0 + 16 + 31) >> 5;

    // prefetch K tile 0 into registers
    short8 kreg[8];
    for (int c = 0; c < 2; ++c) {
        const __hip_bfloat16* Kp = Kb + (size_t)(c * 16 + lane15) * DMODEL + head * HEAD_DIM;
        for (int kk = 0; kk < 4; ++kk)
            kreg[c * 4 + kk] = *(const short8*)(Kp + kk * 32 + quad * 8);
    }

    for (int kt = 0; kt < nkt; ++kt) {
        const int kb = kt * 32;

        // V loads for this tile — issued early, consumed at the bottom
        short8 vreg[8];
        for (int nt = 0; nt < 8; ++nt)
            vreg[nt] = *(const short8*)(Vt + (size_t)(head * HEAD_DIM + nt * 16 + lane15) * S_LEN + kb + quad * 8);

        // QK^T from prefetched K registers
        f32x4 sc[2];
        sc[0] = {0.f, 0.f, 0.f, 0.f};
        sc[1] = {0.f, 0.f, 0.f, 0.f};
        for (int c = 0; c < 2; ++c)
            for (int kk = 0; kk < 4; ++kk)
                sc[c] = __builtin_amdgcn_mfma_f32_16x16x32_bf16(qf[kk], kreg[c * 4 + kk], sc[c], 0, 0, 0);

        // prefetch next K tile (clamped; discarded on last iteration)
        {
            int kbn = (kt + 1 < nkt) ? (kb + 32) : kb;
            for (int c = 0; c < 2; ++c) {
                const __hip_bfloat16* Kp = Kb + (size_t)(kbn + c * 16 + lane15) * DMODEL + head * HEAD_DIM;
                for (int kk = 0; kk < 4; ++kk)
                    kreg[c * 4 + kk] = *(const short8*)(Kp + kk * 32 + quad * 8);
            }
        }

        const bool masked = (kb + 31 > q0);  // only the last tile(s) need causal masking
        const int key0 = kb + lane15;
        const int key1 = kb + 16 + lane15;
        for (int i = 0; i < 4; ++i) {
            // capped score - 10 = 40 - 100/(exp(s/25)+1)  (monotone, exact tanh identity)
            float e0 = __expf(sc[0][i] * K1);
            float e1 = __expf(sc[1][i] * K1);
            float c0 = __builtin_fmaf(-100.0f, __builtin_amdgcn_rcpf(e0 + 1.0f), 40.0f);
            float c1 = __builtin_fmaf(-100.0f, __builtin_amdgcn_rcpf(e1 + 1.0f), 40.0f);
            float p0 = __expf(c0);
            float p1 = __expf(c1);
            if (masked) {
                int q = q0 + quad * 4 + i;
                if (key0 > q) p0 = 0.f;
                if (key1 > q) p1 = 0.f;
            }
            __hip_bfloat16 b0 = f2bf(p0), b1 = f2bf(p1);
            lpart[i] += bf2f(b0) + bf2f(b1);  // l from the SAME bf16-rounded P used in PV
            Pl[wave][quad * 4 + i][lane15] = bf_bits(b0);
            Pl[wave][quad * 4 + i][16 + lane15] = bf_bits(b1);
        }
        // per-wave LDS region: own-wave DS completion is enough (no block barrier)
        asm volatile("s_waitcnt lgkmcnt(0)" ::: "memory");
        ushortv8_a pv = *(const ushortv8_a*)(&Pl[wave][lane15][quad * 8]);
        asm volatile("" ::: "memory");
        short8 pf;
        __builtin_memcpy(&pf, &pv, 16);
        for (int nt = 0; nt < 8; ++nt)
            acc[nt] = __builtin_amdgcn_mfma_f32_16x16x32_bf16(pf, vreg[nt], acc[nt], 0, 0, 0);
    }

    for (int i = 0; i < 4; ++i) {
        float l = lpart[i];
        l += __shfl_xor(l, 1, 64);
        l += __shfl_xor(l, 2, 64);
        l += __shfl_xor(l, 4, 64);
        l += __shfl_xor(l, 8, 64);
        float inv = 1.0f / l;
        int row = q0 + quad * 4 + i;
        for (int nt = 0; nt < 8; ++nt) {
            int col = head * HEAD_DIM + nt * 16 + lane15;
            O[(size_t)row * DMODEL + col] = f2bf(acc[nt][i] * inv);
        }
    }
}

extern "C" void kernel_launch(void* const* d_in, const int* in_sizes, int n_in,
                              void* d_out, int out_size, void* d_ws, size_t ws_size,
                              hipStream_t stream) {
    const float* x  = (const float*)d_in[0];
    const float* wq = (const float*)d_in[1];
    const float* wk = (const float*)d_in[2];
    const float* wv = (const float*)d_in[3];
    const float* wo = (const float*)d_in[4];
    const float* fc = (const float*)d_in[5];
    const float* fs = (const float*)d_in[6];
    float* out = (float*)d_out;

    char* ws = (char*)d_ws;
    const size_t MB8 = (size_t)2048 * 2048 * sizeof(__hip_bfloat16);
    __hip_bfloat16* wq_t = (__hip_bfloat16*)(ws + 0 * MB8);  // -> attn after QKV GEMM
    __hip_bfloat16* wk_t = (__hip_bfloat16*)(ws + 1 * MB8);
    __hip_bfloat16* wv_t = (__hip_bfloat16*)(ws + 2 * MB8);  // -> wo_t after QKV GEMM
    __hip_bfloat16* Qb   = (__hip_bfloat16*)(ws + 3 * MB8);
    __hip_bfloat16* Kbuf = (__hip_bfloat16*)(ws + 4 * MB8);
    __hip_bfloat16* Vt   = (__hip_bfloat16*)(ws + 5 * MB8);
    __hip_bfloat16* attn = wq_t;
    __hip_bfloat16* wo_t = wv_t;
    // x_bf lives in d_out's first 8 MiB: dead before the final GEMM overwrites d_out
    __hip_bfloat16* x_bf = (__hip_bfloat16*)d_out;

    dim3 tb(32, 8);
    dim3 tg(64, 64);

    convert_x<<<16384, 256, 0, stream>>>(x, x_bf);
    transpose_f32<<<tg, tb, 0, stream>>>(wq, wq_t);
    transpose_f32<<<tg, tb, 0, stream>>>(wk, wk_t);
    transpose_f32<<<tg, tb, 0, stream>>>(wv, wv_t);

    gemm_qkv<<<dim3(48, 16), 256, 0, stream>>>(x_bf, wq_t, wk_t, wv_t, Qb, Kbuf, Vt);

    rope_kernel<<<dim3(8192, 2), 256, 0, stream>>>(Qb, Kbuf, fc, fs);

    flash_attn<<<512, 256, 0, stream>>>(Qb, Kbuf, Vt, attn);

    transpose_f32<<<tg, tb, 0, stream>>>(wo, wo_t);
    gemm_out<<<dim3(16, 16), 256, 0, stream>>>(attn, wo_t, out);
}

// Round 6
// 350.583 us; speedup vs baseline: 1.6442x; 1.2445x over previous
//
#include <hip/hip_runtime.h>
#include <hip/hip_bf16.h>

typedef __attribute__((ext_vector_type(8))) short short8;
typedef __attribute__((ext_vector_type(4))) short short4v;
typedef __attribute__((ext_vector_type(4))) float f32x4;
typedef __attribute__((ext_vector_type(4))) float float4v;

#define S_LEN 2048
#define DMODEL 2048
#define N_HEADS 16
#define HEAD_DIM 128

__device__ __forceinline__ float bf2f(__hip_bfloat16 b) { return __bfloat162float(b); }
__device__ __forceinline__ __hip_bfloat16 f2bf(float f) { return __float2bfloat16(f); }
__device__ __forceinline__ short bfs(float f) {
    union { __hip_bfloat16 b; short s; } x; x.b = __float2bfloat16(f); return x.s;
}
__device__ __forceinline__ float sbf(short s) {
    union { short s; __hip_bfloat16 b; } x; x.s = s; return __bfloat162float(x.b);
}

#if __has_builtin(__builtin_amdgcn_global_load_lds)
#define HAVE_ASYNC_LDS 1
#else
#define HAVE_ASYNC_LDS 0
#endif

// Stage 16B per lane into LDS. ldsbase must be wave-uniform; HW scatters lane i at base + 16*i.
__device__ __forceinline__ void stage16(const __hip_bfloat16* g, __hip_bfloat16* ldsbase, int lane) {
#if HAVE_ASYNC_LDS
    __builtin_amdgcn_global_load_lds(
        (const __attribute__((address_space(1))) unsigned int*)g,
        (__attribute__((address_space(3))) unsigned int*)ldsbase,
        16, 0, 0);
#else
    *(short8*)((char*)ldsbase + lane * 16) = *(const short8*)g;
#endif
}

// ---------------- x (f32) -> bf16, vectorized ----------------
__global__ __launch_bounds__(256) void convert_x(const float* __restrict__ in,
                                                 __hip_bfloat16* __restrict__ out) {
    size_t i = ((size_t)blockIdx.x * 256 + threadIdx.x) * 4;
    float4v v = *(const float4v*)(in + i);
    short4v p;
    p.x = bfs(v.x); p.y = bfs(v.y); p.z = bfs(v.z); p.w = bfs(v.w);
    *(short4v*)(out + i) = p;
}

// ---------------- 4 weight transposes in one dispatch (f32 -> bf16) ----------------
__global__ __launch_bounds__(256) void transpose_w4(const float* __restrict__ w0,
                                                    const float* __restrict__ w1,
                                                    const float* __restrict__ w2,
                                                    const float* __restrict__ w3,
                                                    __hip_bfloat16* __restrict__ o0,
                                                    __hip_bfloat16* __restrict__ o1,
                                                    __hip_bfloat16* __restrict__ o2,
                                                    __hip_bfloat16* __restrict__ o3) {
    const float* in = (blockIdx.z == 0) ? w0 : (blockIdx.z == 1) ? w1 : (blockIdx.z == 2) ? w2 : w3;
    __hip_bfloat16* out = (blockIdx.z == 0) ? o0 : (blockIdx.z == 1) ? o1 : (blockIdx.z == 2) ? o2 : o3;
    __shared__ __hip_bfloat16 tile[32][33];
    int bx = blockIdx.x * 32;
    int by = blockIdx.y * 32;
    int tx = threadIdx.x;      // 0..31
    int ty = threadIdx.y;      // 0..7
    for (int i = ty; i < 32; i += 8)
        tile[i][tx] = f2bf(in[(size_t)(by + i) * DMODEL + bx + tx]);
    __syncthreads();
    for (int i = ty; i < 32; i += 8)
        out[(size_t)(bx + i) * DMODEL + by + tx] = tile[tx][i];
}

// ---------------- fused QKV GEMM with RoPE epilogue ----------------
// grid (48,16): blockIdx.x>>4 selects {Q,K,V}. 128x128 tile, BK=32, m97 pattern.
// Q,K: RoPE applied on fp32 accumulators (pair partner via shfl_xor 1) before bf16 store.
// V: C tile stored TRANSPOSED (Vt[d][s]) with packed 4xbf16 stores.
__global__ __launch_bounds__(256) void gemm_qkv(const __hip_bfloat16* __restrict__ A,
                                                const __hip_bfloat16* __restrict__ Bq,
                                                const __hip_bfloat16* __restrict__ Bk,
                                                const __hip_bfloat16* __restrict__ Bv,
                                                __hip_bfloat16* __restrict__ Cq,
                                                __hip_bfloat16* __restrict__ Ck,
                                                __hip_bfloat16* __restrict__ Cvt,
                                                const float* __restrict__ fc,
                                                const float* __restrict__ fs) {
    __shared__ alignas(16) __hip_bfloat16 As[128 * 32];
    __shared__ alignas(16) __hip_bfloat16 Bs[128 * 32];
    const int which = blockIdx.x >> 4;
    const __hip_bfloat16* Bt = (which == 0) ? Bq : (which == 1) ? Bk : Bv;
    const int tid = threadIdx.x;
    const int wave = tid >> 6;
    const int lane = tid & 63;
    const int lane15 = lane & 15;
    const int quad = lane >> 4;
    const int m0 = blockIdx.y * 128;
    const int n0 = (blockIdx.x & 15) * 128;
    const int wm = (wave >> 1) * 64;
    const int wn = (wave & 1) * 64;

    f32x4 acc[4][4];
    for (int i = 0; i < 4; ++i)
        for (int j = 0; j < 4; ++j)
            acc[i][j] = {0.f, 0.f, 0.f, 0.f};

    const int rA = lane >> 2;
    const int cA = (lane & 3) * 8;

    for (int k0 = 0; k0 < DMODEL; k0 += 32) {
        __syncthreads();
        for (int c = 0; c < 4; ++c) {
            int chunk = wave * 4 + c;
            if (chunk < 8) {
                int r = chunk * 16 + rA;
                stage16(A + (size_t)(m0 + r) * DMODEL + k0 + cA, As + chunk * 512, lane);
            } else {
                int r = (chunk - 8) * 16 + rA;
                stage16(Bt + (size_t)(n0 + r) * DMODEL + k0 + cA, Bs + (chunk - 8) * 512, lane);
            }
        }
#if HAVE_ASYNC_LDS
        asm volatile("s_waitcnt vmcnt(0)" ::: "memory");
#endif
        __syncthreads();

        short8 af[4], bfr[4];
        for (int mt = 0; mt < 4; ++mt)
            af[mt] = *(const short8*)(As + (wm + mt * 16 + lane15) * 32 + quad * 8);
        for (int nt = 0; nt < 4; ++nt)
            bfr[nt] = *(const short8*)(Bs + (wn + nt * 16 + lane15) * 32 + quad * 8);
        for (int mt = 0; mt < 4; ++mt)
            for (int nt = 0; nt < 4; ++nt)
                acc[mt][nt] = __builtin_amdgcn_mfma_f32_16x16x32_bf16(af[mt], bfr[nt], acc[mt][nt], 0, 0, 0);
    }

    if (which < 2) {
        __hip_bfloat16* C = (which == 0) ? Cq : Ck;
        for (int mt = 0; mt < 4; ++mt)
            for (int nt = 0; nt < 4; ++nt) {
                int col = n0 + wn + nt * 16 + lane15;
                int j = (col & 127) >> 1;     // freq index within head
                bool odd = col & 1;
                for (int i = 0; i < 4; ++i) {
                    int row = m0 + wm + mt * 16 + quad * 4 + i;  // seq position
                    float v = acc[mt][nt][i];
                    float p = __shfl_xor(v, 1, 64);              // pair partner (col^1)
                    float c = fc[row * 64 + j];
                    float sn = fs[row * 64 + j];
                    float r = odd ? (p * sn + v * c) : (v * c - p * sn);
                    C[(size_t)row * DMODEL + col] = f2bf(r);
                }
            }
    } else {
        for (int mt = 0; mt < 4; ++mt) {
            int rowbase = m0 + wm + mt * 16 + quad * 4;
            for (int nt = 0; nt < 4; ++nt) {
                int col = n0 + wn + nt * 16 + lane15;
                short4v pk;
                pk.x = bfs(acc[mt][nt][0]);
                pk.y = bfs(acc[mt][nt][1]);
                pk.z = bfs(acc[mt][nt][2]);
                pk.w = bfs(acc[mt][nt][3]);
                *(short4v*)(Cvt + (size_t)col * S_LEN + rowbase) = pk;
            }
        }
    }
}

// ---------------- final GEMM: out(f32) = A * Bt^T, 128x64 tiles (2 blocks/CU) ----------------
__global__ __launch_bounds__(256) void gemm_out(const __hip_bfloat16* __restrict__ A,
                                                const __hip_bfloat16* __restrict__ Bt,
                                                float* __restrict__ C) {
    __shared__ alignas(16) __hip_bfloat16 As[128 * 32];
    __shared__ alignas(16) __hip_bfloat16 Bs[64 * 32];
    const int tid = threadIdx.x;
    const int wave = tid >> 6;
    const int lane = tid & 63;
    const int lane15 = lane & 15;
    const int quad = lane >> 4;
    const int m0 = blockIdx.y * 128;
    const int n0 = blockIdx.x * 64;
    const int wm = (wave >> 1) * 64;
    const int wn = (wave & 1) * 32;

    f32x4 acc[4][2];
    for (int i = 0; i < 4; ++i)
        for (int j = 0; j < 2; ++j)
            acc[i][j] = {0.f, 0.f, 0.f, 0.f};

    const int rA = lane >> 2;
    const int cA = (lane & 3) * 8;

    for (int k0 = 0; k0 < DMODEL; k0 += 32) {
        __syncthreads();
        for (int c = 0; c < 3; ++c) {
            int chunk = wave * 3 + c;          // 0..11: 0-7 A, 8-11 B
            if (chunk < 8) {
                int r = chunk * 16 + rA;
                stage16(A + (size_t)(m0 + r) * DMODEL + k0 + cA, As + chunk * 512, lane);
            } else {
                int r = (chunk - 8) * 16 + rA;
                stage16(Bt + (size_t)(n0 + r) * DMODEL + k0 + cA, Bs + (chunk - 8) * 512, lane);
            }
        }
#if HAVE_ASYNC_LDS
        asm volatile("s_waitcnt vmcnt(0)" ::: "memory");
#endif
        __syncthreads();

        short8 af[4], bfr[2];
        for (int mt = 0; mt < 4; ++mt)
            af[mt] = *(const short8*)(As + (wm + mt * 16 + lane15) * 32 + quad * 8);
        for (int nt = 0; nt < 2; ++nt)
            bfr[nt] = *(const short8*)(Bs + (wn + nt * 16 + lane15) * 32 + quad * 8);
        for (int mt = 0; mt < 4; ++mt)
            for (int nt = 0; nt < 2; ++nt)
                acc[mt][nt] = __builtin_amdgcn_mfma_f32_16x16x32_bf16(af[mt], bfr[nt], acc[mt][nt], 0, 0, 0);
    }

    for (int mt = 0; mt < 4; ++mt)
        for (int nt = 0; nt < 2; ++nt)
            for (int i = 0; i < 4; ++i) {
                int row = m0 + wm + mt * 16 + quad * 4 + i;
                int col = n0 + wn + nt * 16 + lane15;
                C[(size_t)row * DMODEL + col] = acc[mt][nt][i];
            }
}

// ---------------- flash attention (LDS-shared K/V, fixed-base softmax) ----------------
// Block = 4 waves, one head, 64-row q-tile (wave w: rows qbase+16w..+15).
// K tile (32x128) and V tile (128x32) staged in LDS once per block, shared by all waves.
// Softcap bounds scores to [-50,50] so p=exp(s-10) is always in fp32/bf16 range:
// fixed-base softmax, no running max / rescale. Balanced pairing: blocks b and b+256
// handle complementary q-blocks so per-CU work is ~constant under round-robin dispatch.
__global__ __launch_bounds__(256) void flash_attn(const __hip_bfloat16* __restrict__ Q,
                                                  const __hip_bfloat16* __restrict__ Kb,
                                                  const __hip_bfloat16* __restrict__ Vt,
                                                  __hip_bfloat16* __restrict__ O) {
    __shared__ alignas(16) short Ks[32][136];   // 272B rows: 16B-aligned, bank-stride 4 -> ~2-way
    __shared__ alignas(16) short Vs[128][40];   // 80B rows: 16B-aligned, bank-stride 20 -> 2-way
    __shared__ alignas(16) short Pl[4][16][40];
    const int tid = threadIdx.x;
    const int wave = tid >> 6;
    const int lane = tid & 63;
    const int lane15 = lane & 15;
    const int quad = lane >> 4;
    const int bx = blockIdx.x;                   // 0..511
    const int u = bx & 255;
    const int head = u & 15;
    const int qp = u >> 4;                       // 0..15
    const int qb = (bx < 256) ? (31 - qp) : qp;  // complementary pairing
    const int qbase = qb * 64;
    const int q0w = qbase + wave * 16;
    const int nkt = 2 * qb + 2;                  // 32-key tiles covering qbase+64
    const float K1 = 0.08838834764831845f * (1.0f / 25.0f);

    const __hip_bfloat16* Qh = Q + (size_t)q0w * DMODEL + head * HEAD_DIM;
    short8 qf[4];
    for (int kk = 0; kk < 4; ++kk)
        qf[kk] = *(const short8*)(Qh + (size_t)lane15 * DMODEL + kk * 32 + quad * 8);

    f32x4 acc[8];
    for (int i = 0; i < 8; ++i) acc[i] = {0.f, 0.f, 0.f, 0.f};
    float lpart[4] = {0.f, 0.f, 0.f, 0.f};

    // staging assignment (256 threads, 16 elems each per matrix)
    const int krow = tid >> 3, kcol = (tid & 7) * 16;  // K: 32 rows x 128 cols
    const int vrow = tid >> 1, vcol = (tid & 1) * 16;  // V: 128 rows x 32 cols
    const __hip_bfloat16* Kg = Kb + (size_t)krow * DMODEL + head * HEAD_DIM + kcol;
    const __hip_bfloat16* Vg = Vt + (size_t)(head * HEAD_DIM + vrow) * S_LEN + vcol;

    // prefetch tile 0
    short8 gk0 = *(const short8*)(Kg);
    short8 gk1 = *(const short8*)(Kg + 8);
    short8 gv0 = *(const short8*)(Vg);
    short8 gv1 = *(const short8*)(Vg + 8);

    for (int kt = 0; kt < nkt; ++kt) {
        const int kb = kt * 32;
        __syncthreads();  // previous tile's LDS reads complete
        *(short8*)&Ks[krow][kcol] = gk0;
        *(short8*)&Ks[krow][kcol + 8] = gk1;
        *(short8*)&Vs[vrow][vcol] = gv0;
        *(short8*)&Vs[vrow][vcol + 8] = gv1;
        __syncthreads();  // staging visible

        // prefetch next tile (overlaps compute)
        if (kt + 1 < nkt) {
            const __hip_bfloat16* Kg2 = Kg + (size_t)(kb + 32) * DMODEL;
            const __hip_bfloat16* Vg2 = Vg + kb + 32;
            gk0 = *(const short8*)(Kg2);
            gk1 = *(const short8*)(Kg2 + 8);
            gv0 = *(const short8*)(Vg2);
            gv1 = *(const short8*)(Vg2 + 8);
        }

        if (kb <= q0w + 15) {  // wave-uniform: skip fully-masked tiles
            f32x4 sc[2];
            sc[0] = {0.f, 0.f, 0.f, 0.f};
            sc[1] = {0.f, 0.f, 0.f, 0.f};
            for (int c = 0; c < 2; ++c)
                for (int kk = 0; kk < 4; ++kk) {
                    short8 kf = *(const short8*)&Ks[c * 16 + lane15][kk * 32 + quad * 8];
                    sc[c] = __builtin_amdgcn_mfma_f32_16x16x32_bf16(qf[kk], kf, sc[c], 0, 0, 0);
                }

            const bool masked = (kb + 31 > q0w);
            const int key0 = kb + lane15;
            const int key1 = kb + 16 + lane15;
            for (int i = 0; i < 4; ++i) {
                // capped-10 = 40 - 100/(exp(s/25)+1) (exact tanh identity); p = exp(.)
                float e0 = __expf(sc[0][i] * K1);
                float e1 = __expf(sc[1][i] * K1);
                float c0 = __builtin_fmaf(-100.0f, __builtin_amdgcn_rcpf(e0 + 1.0f), 40.0f);
                float c1 = __builtin_fmaf(-100.0f, __builtin_amdgcn_rcpf(e1 + 1.0f), 40.0f);
                float p0 = __expf(c0);
                float p1 = __expf(c1);
                if (masked) {
                    int q = q0w + quad * 4 + i;
                    if (key0 > q) p0 = 0.f;
                    if (key1 > q) p1 = 0.f;
                }
                short b0 = bfs(p0), b1 = bfs(p1);
                lpart[i] += sbf(b0) + sbf(b1);  // l from the SAME bf16-rounded P used in PV
                Pl[wave][quad * 4 + i][lane15] = b0;
                Pl[wave][quad * 4 + i][16 + lane15] = b1;
            }
            asm volatile("s_waitcnt lgkmcnt(0)" ::: "memory");  // own-wave P stores done
            short8 pf = *(const short8*)&Pl[wave][lane15][quad * 8];
            asm volatile("" ::: "memory");
            for (int nt = 0; nt < 8; ++nt) {
                short8 vf = *(const short8*)&Vs[nt * 16 + lane15][quad * 8];
                acc[nt] = __builtin_amdgcn_mfma_f32_16x16x32_bf16(pf, vf, acc[nt], 0, 0, 0);
            }
        }
    }

    for (int i = 0; i < 4; ++i) {
        float l = lpart[i];
        l += __shfl_xor(l, 1, 64);
        l += __shfl_xor(l, 2, 64);
        l += __shfl_xor(l, 4, 64);
        l += __shfl_xor(l, 8, 64);
        float inv = 1.0f / l;
        int row = q0w + quad * 4 + i;
        for (int nt = 0; nt < 8; ++nt) {
            int col = head * HEAD_DIM + nt * 16 + lane15;
            O[(size_t)row * DMODEL + col] = f2bf(acc[nt][i] * inv);
        }
    }
}

extern "C" void kernel_launch(void* const* d_in, const int* in_sizes, int n_in,
                              void* d_out, int out_size, void* d_ws, size_t ws_size,
                              hipStream_t stream) {
    const float* x  = (const float*)d_in[0];
    const float* wq = (const float*)d_in[1];
    const float* wk = (const float*)d_in[2];
    const float* wv = (const float*)d_in[3];
    const float* wo = (const float*)d_in[4];
    const float* fc = (const float*)d_in[5];
    const float* fs = (const float*)d_in[6];
    float* out = (float*)d_out;

    char* ws = (char*)d_ws;
    const size_t MB8 = (size_t)2048 * 2048 * sizeof(__hip_bfloat16);
    __hip_bfloat16* wq_t = (__hip_bfloat16*)(ws + 0 * MB8);  // -> attn after QKV GEMM
    __hip_bfloat16* wk_t = (__hip_bfloat16*)(ws + 1 * MB8);
    __hip_bfloat16* wv_t = (__hip_bfloat16*)(ws + 2 * MB8);  // -> wo_t after QKV GEMM
    __hip_bfloat16* wo_t2 = (__hip_bfloat16*)(ws + 2 * MB8);
    __hip_bfloat16* Qb   = (__hip_bfloat16*)(ws + 3 * MB8);
    __hip_bfloat16* Kbuf = (__hip_bfloat16*)(ws + 4 * MB8);
    __hip_bfloat16* Vt   = (__hip_bfloat16*)(ws + 5 * MB8);
    __hip_bfloat16* attn = wq_t;
    // x_bf lives in d_out's first 8 MiB: dead before the final GEMM overwrites d_out
    __hip_bfloat16* x_bf = (__hip_bfloat16*)d_out;

    convert_x<<<4096, 256, 0, stream>>>(x, x_bf);
    // transpose all four weights in one dispatch (wo into its own slot is reused later)
    transpose_w4<<<dim3(64, 64, 4), dim3(32, 8), 0, stream>>>(wq, wk, wv, wo,
                                                              wq_t, wk_t, wv_t, Vt /*temp for wo*/);

    // NOTE: wo_t is parked in Vt's slot only until gemm_qkv needs Vt? No — gemm_qkv writes Vt.
    // Park wo transposed separately: redo wo transpose after QKV into wv_t (freed then).
    gemm_qkv<<<dim3(48, 16), 256, 0, stream>>>(x_bf, wq_t, wk_t, wv_t, Qb, Kbuf, Vt, fc, fs);
    // wv_t now dead; transpose wo into it (single-matrix pass via transpose_w4 z=3 slot trick)
    transpose_w4<<<dim3(64, 64, 1), dim3(32, 8), 0, stream>>>(wo, wo, wo, wo,
                                                              wo_t2, wo_t2, wo_t2, wo_t2);

    flash_attn<<<512, 256, 0, stream>>>(Qb, Kbuf, Vt, attn);

    gemm_out<<<dim3(32, 16), 256, 0, stream>>>(attn, wo_t2, out);
}

// Round 7
// 321.599 us; speedup vs baseline: 1.7923x; 1.0901x over previous
//
#include <hip/hip_runtime.h>
#include <hip/hip_bf16.h>

typedef __attribute__((ext_vector_type(8))) short short8;
typedef __attribute__((ext_vector_type(4))) short short4v;
typedef __attribute__((ext_vector_type(4))) float f32x4;
typedef __attribute__((ext_vector_type(4))) float float4v;

#define S_LEN 2048
#define DMODEL 2048
#define N_HEADS 16
#define HEAD_DIM 128

__device__ __forceinline__ float bf2f(__hip_bfloat16 b) { return __bfloat162float(b); }
__device__ __forceinline__ __hip_bfloat16 f2bf(float f) { return __float2bfloat16(f); }
__device__ __forceinline__ short bfs(float f) {
    union { __hip_bfloat16 b; short s; } x; x.b = __float2bfloat16(f); return x.s;
}
__device__ __forceinline__ float sbf(short s) {
    union { short s; __hip_bfloat16 b; } x; x.s = s; return __bfloat162float(x.b);
}

#if __has_builtin(__builtin_amdgcn_global_load_lds)
#define HAVE_ASYNC_LDS 1
#else
#define HAVE_ASYNC_LDS 0
#endif

// Stage 16B per lane into LDS. ldsbase must be wave-uniform; HW scatters lane i at base + 16*i.
__device__ __forceinline__ void stage16(const __hip_bfloat16* g, __hip_bfloat16* ldsbase, int lane) {
#if HAVE_ASYNC_LDS
    __builtin_amdgcn_global_load_lds(
        (const __attribute__((address_space(1))) unsigned int*)g,
        (__attribute__((address_space(3))) unsigned int*)ldsbase,
        16, 0, 0);
#else
    *(short8*)((char*)ldsbase + lane * 16) = *(const short8*)g;
#endif
}

// ---------------- prep: 4 weight transposes (f32->bf16) + x conversion, one dispatch ----------------
__global__ __launch_bounds__(256) void prep(const float* __restrict__ x,
                                            const float* __restrict__ w0,
                                            const float* __restrict__ w1,
                                            const float* __restrict__ w2,
                                            const float* __restrict__ w3,
                                            __hip_bfloat16* __restrict__ xb,
                                            __hip_bfloat16* __restrict__ o0,
                                            __hip_bfloat16* __restrict__ o1,
                                            __hip_bfloat16* __restrict__ o2,
                                            __hip_bfloat16* __restrict__ o3) {
    const int z = blockIdx.z;
    if (z == 4) {  // x -> bf16, 1024 elems per block
        size_t base = ((size_t)(blockIdx.y * 64 + blockIdx.x) * 256 + (threadIdx.y * 32 + threadIdx.x)) * 4;
        float4v v = *(const float4v*)(x + base);
        short4v p;
        p.x = bfs(v.x); p.y = bfs(v.y); p.z = bfs(v.z); p.w = bfs(v.w);
        *(short4v*)(xb + base) = p;
        return;
    }
    const float* in = (z == 0) ? w0 : (z == 1) ? w1 : (z == 2) ? w2 : w3;
    __hip_bfloat16* out = (z == 0) ? o0 : (z == 1) ? o1 : (z == 2) ? o2 : o3;
    __shared__ __hip_bfloat16 tile[32][33];
    int bx = blockIdx.x * 32;
    int by = blockIdx.y * 32;
    int tx = threadIdx.x;      // 0..31
    int ty = threadIdx.y;      // 0..7
    for (int i = ty; i < 32; i += 8)
        tile[i][tx] = f2bf(in[(size_t)(by + i) * DMODEL + bx + tx]);
    __syncthreads();
    for (int i = ty; i < 32; i += 8)
        out[(size_t)(bx + i) * DMODEL + by + tx] = tile[tx][i];
}

// ---------------- fused QKV GEMM with RoPE epilogue, K-pair staging ----------------
// grid (48,16): blockIdx.x>>4 selects {Q,K,V}. 128x128 tile, BK=64 via two BK=32 LDS sets
// (one barrier window per 64 K) — halves the vmcnt(0)+barrier drains of the m97 loop.
__global__ __launch_bounds__(256) void gemm_qkv(const __hip_bfloat16* __restrict__ A,
                                                const __hip_bfloat16* __restrict__ Bq,
                                                const __hip_bfloat16* __restrict__ Bk,
                                                const __hip_bfloat16* __restrict__ Bv,
                                                __hip_bfloat16* __restrict__ Cq,
                                                __hip_bfloat16* __restrict__ Ck,
                                                __hip_bfloat16* __restrict__ Cvt,
                                                const float* __restrict__ fc,
                                                const float* __restrict__ fs) {
    __shared__ alignas(16) __hip_bfloat16 As[2][128 * 32];
    __shared__ alignas(16) __hip_bfloat16 Bs[2][128 * 32];
    const int which = blockIdx.x >> 4;
    const __hip_bfloat16* Bt = (which == 0) ? Bq : (which == 1) ? Bk : Bv;
    const int tid = threadIdx.x;
    const int wave = tid >> 6;
    const int lane = tid & 63;
    const int lane15 = lane & 15;
    const int quad = lane >> 4;
    const int m0 = blockIdx.y * 128;
    const int n0 = (blockIdx.x & 15) * 128;
    const int wm = (wave >> 1) * 64;
    const int wn = (wave & 1) * 64;

    f32x4 acc[4][4];
    for (int i = 0; i < 4; ++i)
        for (int j = 0; j < 4; ++j)
            acc[i][j] = {0.f, 0.f, 0.f, 0.f};

    const int rA = lane >> 2;
    const int cA = (lane & 3) * 8;

    for (int k0 = 0; k0 < DMODEL; k0 += 64) {
        __syncthreads();
        for (int h = 0; h < 2; ++h) {
            int kk = k0 + h * 32;
            for (int c = 0; c < 4; ++c) {
                int chunk = wave * 4 + c;
                if (chunk < 8) {
                    int r = chunk * 16 + rA;
                    stage16(A + (size_t)(m0 + r) * DMODEL + kk + cA, As[h] + chunk * 512, lane);
                } else {
                    int r = (chunk - 8) * 16 + rA;
                    stage16(Bt + (size_t)(n0 + r) * DMODEL + kk + cA, Bs[h] + (chunk - 8) * 512, lane);
                }
            }
        }
#if HAVE_ASYNC_LDS
        asm volatile("s_waitcnt vmcnt(0)" ::: "memory");
#endif
        __syncthreads();

        for (int h = 0; h < 2; ++h) {
            short8 af[4], bfr[4];
            for (int mt = 0; mt < 4; ++mt)
                af[mt] = *(const short8*)(As[h] + (wm + mt * 16 + lane15) * 32 + quad * 8);
            for (int nt = 0; nt < 4; ++nt)
                bfr[nt] = *(const short8*)(Bs[h] + (wn + nt * 16 + lane15) * 32 + quad * 8);
            for (int mt = 0; mt < 4; ++mt)
                for (int nt = 0; nt < 4; ++nt)
                    acc[mt][nt] = __builtin_amdgcn_mfma_f32_16x16x32_bf16(af[mt], bfr[nt], acc[mt][nt], 0, 0, 0);
        }
    }

    if (which < 2) {
        __hip_bfloat16* C = (which == 0) ? Cq : Ck;
        for (int mt = 0; mt < 4; ++mt)
            for (int nt = 0; nt < 4; ++nt) {
                int col = n0 + wn + nt * 16 + lane15;
                int j = (col & 127) >> 1;     // freq index within head
                bool odd = col & 1;
                for (int i = 0; i < 4; ++i) {
                    int row = m0 + wm + mt * 16 + quad * 4 + i;  // seq position
                    float v = acc[mt][nt][i];
                    float p = __shfl_xor(v, 1, 64);              // pair partner (col^1)
                    float c = fc[row * 64 + j];
                    float sn = fs[row * 64 + j];
                    float r = odd ? (p * sn + v * c) : (v * c - p * sn);
                    C[(size_t)row * DMODEL + col] = f2bf(r);
                }
            }
    } else {
        for (int mt = 0; mt < 4; ++mt) {
            int rowbase = m0 + wm + mt * 16 + quad * 4;
            for (int nt = 0; nt < 4; ++nt) {
                int col = n0 + wn + nt * 16 + lane15;
                short4v pk;
                pk.x = bfs(acc[mt][nt][0]);
                pk.y = bfs(acc[mt][nt][1]);
                pk.z = bfs(acc[mt][nt][2]);
                pk.w = bfs(acc[mt][nt][3]);
                *(short4v*)(Cvt + (size_t)col * S_LEN + rowbase) = pk;
            }
        }
    }
}

// ---------------- final GEMM: out(f32) = A * Bt^T, 128x64 tiles, K-pair staging ----------------
__global__ __launch_bounds__(256) void gemm_out(const __hip_bfloat16* __restrict__ A,
                                                const __hip_bfloat16* __restrict__ Bt,
                                                float* __restrict__ C) {
    __shared__ alignas(16) __hip_bfloat16 As[2][128 * 32];
    __shared__ alignas(16) __hip_bfloat16 Bs[2][64 * 32];
    const int tid = threadIdx.x;
    const int wave = tid >> 6;
    const int lane = tid & 63;
    const int lane15 = lane & 15;
    const int quad = lane >> 4;
    const int m0 = blockIdx.y * 128;
    const int n0 = blockIdx.x * 64;
    const int wm = (wave >> 1) * 64;
    const int wn = (wave & 1) * 32;

    f32x4 acc[4][2];
    for (int i = 0; i < 4; ++i)
        for (int j = 0; j < 2; ++j)
            acc[i][j] = {0.f, 0.f, 0.f, 0.f};

    const int rA = lane >> 2;
    const int cA = (lane & 3) * 8;

    for (int k0 = 0; k0 < DMODEL; k0 += 64) {
        __syncthreads();
        for (int h = 0; h < 2; ++h) {
            int kk = k0 + h * 32;
            for (int c = 0; c < 3; ++c) {
                int chunk = wave * 3 + c;          // 0..11: 0-7 A, 8-11 B
                if (chunk < 8) {
                    int r = chunk * 16 + rA;
                    stage16(A + (size_t)(m0 + r) * DMODEL + kk + cA, As[h] + chunk * 512, lane);
                } else {
                    int r = (chunk - 8) * 16 + rA;
                    stage16(Bt + (size_t)(n0 + r) * DMODEL + kk + cA, Bs[h] + (chunk - 8) * 512, lane);
                }
            }
        }
#if HAVE_ASYNC_LDS
        asm volatile("s_waitcnt vmcnt(0)" ::: "memory");
#endif
        __syncthreads();

        for (int h = 0; h < 2; ++h) {
            short8 af[4], bfr[2];
            for (int mt = 0; mt < 4; ++mt)
                af[mt] = *(const short8*)(As[h] + (wm + mt * 16 + lane15) * 32 + quad * 8);
            for (int nt = 0; nt < 2; ++nt)
                bfr[nt] = *(const short8*)(Bs[h] + (wn + nt * 16 + lane15) * 32 + quad * 8);
            for (int mt = 0; mt < 4; ++mt)
                for (int nt = 0; nt < 2; ++nt)
                    acc[mt][nt] = __builtin_amdgcn_mfma_f32_16x16x32_bf16(af[mt], bfr[nt], acc[mt][nt], 0, 0, 0);
        }
    }

    for (int mt = 0; mt < 4; ++mt)
        for (int nt = 0; nt < 2; ++nt)
            for (int i = 0; i < 4; ++i) {
                int row = m0 + wm + mt * 16 + quad * 4 + i;
                int col = n0 + wn + nt * 16 + lane15;
                C[(size_t)row * DMODEL + col] = acc[mt][nt][i];
            }
}

// ---------------- flash attention (LDS-shared K/V, fixed-base softmax) ----------------
// Block = 4 waves, one head, 64-row q-tile. K (32x128) and V (128x32) staged once per
// block into padded LDS, shared by all 4 waves. Softcap bounds scores to [-50,50] so
// p=exp(s-10) is always in range: fixed-base softmax, no running max / rescale.
// Blocks b and b+256 take complementary q-blocks for round-robin load balance.
__global__ __launch_bounds__(256) void flash_attn(const __hip_bfloat16* __restrict__ Q,
                                                  const __hip_bfloat16* __restrict__ Kb,
                                                  const __hip_bfloat16* __restrict__ Vt,
                                                  __hip_bfloat16* __restrict__ O) {
    __shared__ alignas(16) short Ks[32][136];
    __shared__ alignas(16) short Vs[128][40];
    __shared__ alignas(16) short Pl[4][16][40];
    const int tid = threadIdx.x;
    const int wave = tid >> 6;
    const int lane = tid & 63;
    const int lane15 = lane & 15;
    const int quad = lane >> 4;
    const int bx = blockIdx.x;                   // 0..511
    const int u = bx & 255;
    const int head = u & 15;
    const int qp = u >> 4;                       // 0..15
    const int qb = (bx < 256) ? (31 - qp) : qp;  // complementary pairing
    const int qbase = qb * 64;
    const int q0w = qbase + wave * 16;
    const int nkt = 2 * qb + 2;                  // 32-key tiles covering qbase+64
    const float K1 = 0.08838834764831845f * (1.0f / 25.0f);

    const __hip_bfloat16* Qh = Q + (size_t)q0w * DMODEL + head * HEAD_DIM;
    short8 qf[4];
    for (int kk = 0; kk < 4; ++kk)
        qf[kk] = *(const short8*)(Qh + (size_t)lane15 * DMODEL + kk * 32 + quad * 8);

    f32x4 acc[8];
    for (int i = 0; i < 8; ++i) acc[i] = {0.f, 0.f, 0.f, 0.f};
    float lpart[4] = {0.f, 0.f, 0.f, 0.f};

    const int krow = tid >> 3, kcol = (tid & 7) * 16;  // K: 32 rows x 128 cols
    const int vrow = tid >> 1, vcol = (tid & 1) * 16;  // V: 128 rows x 32 cols
    const __hip_bfloat16* Kg = Kb + (size_t)krow * DMODEL + head * HEAD_DIM + kcol;
    const __hip_bfloat16* Vg = Vt + (size_t)(head * HEAD_DIM + vrow) * S_LEN + vcol;

    short8 gk0 = *(const short8*)(Kg);
    short8 gk1 = *(const short8*)(Kg + 8);
    short8 gv0 = *(const short8*)(Vg);
    short8 gv1 = *(const short8*)(Vg + 8);

    for (int kt = 0; kt < nkt; ++kt) {
        const int kb = kt * 32;
        __syncthreads();
        *(short8*)&Ks[krow][kcol] = gk0;
        *(short8*)&Ks[krow][kcol + 8] = gk1;
        *(short8*)&Vs[vrow][vcol] = gv0;
        *(short8*)&Vs[vrow][vcol + 8] = gv1;
        __syncthreads();

        if (kt + 1 < nkt) {
            const __hip_bfloat16* Kg2 = Kg + (size_t)(kb + 32) * DMODEL;
            const __hip_bfloat16* Vg2 = Vg + kb + 32;
            gk0 = *(const short8*)(Kg2);
            gk1 = *(const short8*)(Kg2 + 8);
            gv0 = *(const short8*)(Vg2);
            gv1 = *(const short8*)(Vg2 + 8);
        }

        if (kb <= q0w + 15) {  // wave-uniform: skip fully-masked tiles
            f32x4 sc[2];
            sc[0] = {0.f, 0.f, 0.f, 0.f};
            sc[1] = {0.f, 0.f, 0.f, 0.f};
            for (int c = 0; c < 2; ++c)
                for (int kk = 0; kk < 4; ++kk) {
                    short8 kf = *(const short8*)&Ks[c * 16 + lane15][kk * 32 + quad * 8];
                    sc[c] = __builtin_amdgcn_mfma_f32_16x16x32_bf16(qf[kk], kf, sc[c], 0, 0, 0);
                }

            const bool masked = (kb + 31 > q0w);
            const int key0 = kb + lane15;
            const int key1 = kb + 16 + lane15;
            for (int i = 0; i < 4; ++i) {
                float e0 = __expf(sc[0][i] * K1);
                float e1 = __expf(sc[1][i] * K1);
                float c0 = __builtin_fmaf(-100.0f, __builtin_amdgcn_rcpf(e0 + 1.0f), 40.0f);
                float c1 = __builtin_fmaf(-100.0f, __builtin_amdgcn_rcpf(e1 + 1.0f), 40.0f);
                float p0 = __expf(c0);
                float p1 = __expf(c1);
                if (masked) {
                    int q = q0w + quad * 4 + i;
                    if (key0 > q) p0 = 0.f;
                    if (key1 > q) p1 = 0.f;
                }
                short b0 = bfs(p0), b1 = bfs(p1);
                lpart[i] += sbf(b0) + sbf(b1);
                Pl[wave][quad * 4 + i][lane15] = b0;
                Pl[wave][quad * 4 + i][16 + lane15] = b1;
            }
            asm volatile("s_waitcnt lgkmcnt(0)" ::: "memory");
            short8 pf = *(const short8*)&Pl[wave][lane15][quad * 8];
            asm volatile("" ::: "memory");
            for (int nt = 0; nt < 8; ++nt) {
                short8 vf = *(const short8*)&Vs[nt * 16 + lane15][quad * 8];
                acc[nt] = __builtin_amdgcn_mfma_f32_16x16x32_bf16(pf, vf, acc[nt], 0, 0, 0);
            }
        }
    }

    for (int i = 0; i < 4; ++i) {
        float l = lpart[i];
        l += __shfl_xor(l, 1, 64);
        l += __shfl_xor(l, 2, 64);
        l += __shfl_xor(l, 4, 64);
        l += __shfl_xor(l, 8, 64);
        float inv = 1.0f / l;
        int row = q0w + quad * 4 + i;
        for (int nt = 0; nt < 8; ++nt) {
            int col = head * HEAD_DIM + nt * 16 + lane15;
            O[(size_t)row * DMODEL + col] = f2bf(acc[nt][i] * inv);
        }
    }
}

extern "C" void kernel_launch(void* const* d_in, const int* in_sizes, int n_in,
                              void* d_out, int out_size, void* d_ws, size_t ws_size,
                              hipStream_t stream) {
    const float* x  = (const float*)d_in[0];
    const float* wq = (const float*)d_in[1];
    const float* wk = (const float*)d_in[2];
    const float* wv = (const float*)d_in[3];
    const float* wo = (const float*)d_in[4];
    const float* fc = (const float*)d_in[5];
    const float* fs = (const float*)d_in[6];
    float* out = (float*)d_out;

    char* ws = (char*)d_ws;
    const size_t MB8 = (size_t)2048 * 2048 * sizeof(__hip_bfloat16);
    __hip_bfloat16* wq_t = (__hip_bfloat16*)(ws + 0 * MB8);  // -> attn after QKV GEMM
    __hip_bfloat16* wk_t = (__hip_bfloat16*)(ws + 1 * MB8);
    __hip_bfloat16* wv_t = (__hip_bfloat16*)(ws + 2 * MB8);
    __hip_bfloat16* wo_t = (__hip_bfloat16*)(ws + 3 * MB8);
    __hip_bfloat16* Qb   = (__hip_bfloat16*)(ws + 4 * MB8);
    __hip_bfloat16* Kbuf = (__hip_bfloat16*)(ws + 5 * MB8);
    __hip_bfloat16* Vt   = (__hip_bfloat16*)(ws + 6 * MB8);
    __hip_bfloat16* attn = wq_t;
    // x_bf lives in d_out's first 8 MiB: dead before the final GEMM overwrites d_out
    __hip_bfloat16* x_bf = (__hip_bfloat16*)d_out;

    prep<<<dim3(64, 64, 5), dim3(32, 8), 0, stream>>>(x, wq, wk, wv, wo,
                                                      x_bf, wq_t, wk_t, wv_t, wo_t);

    gemm_qkv<<<dim3(48, 16), 256, 0, stream>>>(x_bf, wq_t, wk_t, wv_t, Qb, Kbuf, Vt, fc, fs);

    flash_attn<<<512, 256, 0, stream>>>(Qb, Kbuf, Vt, attn);

    gemm_out<<<dim3(32, 16), 256, 0, stream>>>(attn, wo_t, out);
}

// Round 8
// 307.877 us; speedup vs baseline: 1.8722x; 1.0446x over previous
//
#include <hip/hip_runtime.h>
#include <hip/hip_bf16.h>

typedef __attribute__((ext_vector_type(8))) short short8;
typedef __attribute__((ext_vector_type(4))) short short4v;
typedef __attribute__((ext_vector_type(4))) float f32x4;
typedef __attribute__((ext_vector_type(4))) float float4v;

#define S_LEN 2048
#define DMODEL 2048
#define N_HEADS 16
#define HEAD_DIM 128

__device__ __forceinline__ float bf2f(__hip_bfloat16 b) { return __bfloat162float(b); }
__device__ __forceinline__ __hip_bfloat16 f2bf(float f) { return __float2bfloat16(f); }
__device__ __forceinline__ short bfs(float f) {
    union { __hip_bfloat16 b; short s; } x; x.b = __float2bfloat16(f); return x.s;
}
__device__ __forceinline__ float sbf(short s) {
    union { short s; __hip_bfloat16 b; } x; x.s = s; return __bfloat162float(x.b);
}

#if __has_builtin(__builtin_amdgcn_global_load_lds)
#define HAVE_ASYNC_LDS 1
#else
#define HAVE_ASYNC_LDS 0
#endif

// Stage 16B per lane into LDS. ldsbase must be wave-uniform; HW scatters lane i at base + 16*i.
__device__ __forceinline__ void stage16(const __hip_bfloat16* g, __hip_bfloat16* ldsbase, int lane) {
#if HAVE_ASYNC_LDS
    __builtin_amdgcn_global_load_lds(
        (const __attribute__((address_space(1))) unsigned int*)g,
        (__attribute__((address_space(3))) unsigned int*)ldsbase,
        16, 0, 0);
#else
    *(short8*)((char*)ldsbase + lane * 16) = *(const short8*)g;
#endif
}

// ---------------- prep: 4 weight transposes (f32->bf16, vectorized) + x conversion ----------------
// grid (32,32,5), 256 threads. z<4: 64x64 transpose tiles; z==4: x convert (16 elems/thread).
__global__ __launch_bounds__(256) void prep(const float* __restrict__ x,
                                            const float* __restrict__ w0,
                                            const float* __restrict__ w1,
                                            const float* __restrict__ w2,
                                            const float* __restrict__ w3,
                                            __hip_bfloat16* __restrict__ xb,
                                            __hip_bfloat16* __restrict__ o0,
                                            __hip_bfloat16* __restrict__ o1,
                                            __hip_bfloat16* __restrict__ o2,
                                            __hip_bfloat16* __restrict__ o3) {
    const int z = blockIdx.z;
    const int tid = threadIdx.x;
    if (z == 4) {
        size_t base = (((size_t)blockIdx.y * 32 + blockIdx.x) * 256 + tid) * 16;
        for (int i = 0; i < 4; ++i) {
            float4v v = *(const float4v*)(x + base + i * 4);
            short4v p;
            p.x = bfs(v.x); p.y = bfs(v.y); p.z = bfs(v.z); p.w = bfs(v.w);
            *(short4v*)((short*)xb + base + i * 4) = p;
        }
        return;
    }
    const float* in = (z == 0) ? w0 : (z == 1) ? w1 : (z == 2) ? w2 : w3;
    __hip_bfloat16* out = (z == 0) ? o0 : (z == 1) ? o1 : (z == 2) ? o2 : o3;
    __shared__ short tile[64][68];
    const int bx = blockIdx.x * 64;
    const int by = blockIdx.y * 64;
    const int c4 = (tid & 15) * 4;
    for (int rr = 0; rr < 4; ++rr) {
        int r = (tid >> 4) + rr * 16;
        float4v v = *(const float4v*)(in + (size_t)(by + r) * DMODEL + bx + c4);
        short4v p;
        p.x = bfs(v.x); p.y = bfs(v.y); p.z = bfs(v.z); p.w = bfs(v.w);
        *(short4v*)&tile[r][c4] = p;
    }
    __syncthreads();
    const int oc = tid >> 2;
    const int s0 = (tid & 3) * 16;
    short8 a, b;
    for (int i = 0; i < 8; ++i) ((short*)&a)[i] = tile[s0 + i][oc];
    for (int i = 0; i < 8; ++i) ((short*)&b)[i] = tile[s0 + 8 + i][oc];
    *(short8*)((short*)out + (size_t)(bx + oc) * DMODEL + by + s0) = a;
    *(short8*)((short*)out + (size_t)(bx + oc) * DMODEL + by + s0 + 8) = b;
}

// ---------------- split-K QKV GEMM ----------------
// grid (96,16): bx>>5 selects {Q,K,V}, (bx>>4)&1 selects K-half, bx&15 = n-tile.
// 128x128 tile, BK=32, m97 staging. Partials written as bf16 (V pre-transposed).
__global__ __launch_bounds__(256) void gemm_qkv_sk(const __hip_bfloat16* __restrict__ A,
                                                   const __hip_bfloat16* __restrict__ Bq,
                                                   const __hip_bfloat16* __restrict__ Bk,
                                                   const __hip_bfloat16* __restrict__ Bv,
                                                   __hip_bfloat16* __restrict__ Q0,
                                                   __hip_bfloat16* __restrict__ Q1,
                                                   __hip_bfloat16* __restrict__ K0,
                                                   __hip_bfloat16* __restrict__ K1,
                                                   __hip_bfloat16* __restrict__ V0t,
                                                   __hip_bfloat16* __restrict__ V1t) {
    __shared__ alignas(16) __hip_bfloat16 As[128 * 32];
    __shared__ alignas(16) __hip_bfloat16 Bs[128 * 32];
    const int bx = blockIdx.x;
    const int which = bx >> 5;
    const int kh = (bx >> 4) & 1;
    const __hip_bfloat16* Bt = (which == 0) ? Bq : (which == 1) ? Bk : Bv;
    const int tid = threadIdx.x;
    const int wave = tid >> 6;
    const int lane = tid & 63;
    const int lane15 = lane & 15;
    const int quad = lane >> 4;
    const int m0 = blockIdx.y * 128;
    const int n0 = (bx & 15) * 128;
    const int wm = (wave >> 1) * 64;
    const int wn = (wave & 1) * 64;

    f32x4 acc[4][4];
    for (int i = 0; i < 4; ++i)
        for (int j = 0; j < 4; ++j)
            acc[i][j] = {0.f, 0.f, 0.f, 0.f};

    const int rA = lane >> 2;
    const int cA = (lane & 3) * 8;
    const int kbeg = kh * 1024;

    for (int k0 = kbeg; k0 < kbeg + 1024; k0 += 32) {
        __syncthreads();
        for (int c = 0; c < 4; ++c) {
            int chunk = wave * 4 + c;
            if (chunk < 8) {
                int r = chunk * 16 + rA;
                stage16(A + (size_t)(m0 + r) * DMODEL + k0 + cA, As + chunk * 512, lane);
            } else {
                int r = (chunk - 8) * 16 + rA;
                stage16(Bt + (size_t)(n0 + r) * DMODEL + k0 + cA, Bs + (chunk - 8) * 512, lane);
            }
        }
#if HAVE_ASYNC_LDS
        asm volatile("s_waitcnt vmcnt(0)" ::: "memory");
#endif
        __syncthreads();

        short8 af[4], bfr[4];
        for (int mt = 0; mt < 4; ++mt)
            af[mt] = *(const short8*)(As + (wm + mt * 16 + lane15) * 32 + quad * 8);
        for (int nt = 0; nt < 4; ++nt)
            bfr[nt] = *(const short8*)(Bs + (wn + nt * 16 + lane15) * 32 + quad * 8);
        for (int mt = 0; mt < 4; ++mt)
            for (int nt = 0; nt < 4; ++nt)
                acc[mt][nt] = __builtin_amdgcn_mfma_f32_16x16x32_bf16(af[mt], bfr[nt], acc[mt][nt], 0, 0, 0);
    }

    if (which < 2) {
        __hip_bfloat16* C = (which == 0) ? (kh ? Q1 : Q0) : (kh ? K1 : K0);
        for (int mt = 0; mt < 4; ++mt)
            for (int nt = 0; nt < 4; ++nt)
                for (int i = 0; i < 4; ++i) {
                    int row = m0 + wm + mt * 16 + quad * 4 + i;
                    int col = n0 + wn + nt * 16 + lane15;
                    C[(size_t)row * DMODEL + col] = f2bf(acc[mt][nt][i]);
                }
    } else {
        __hip_bfloat16* Vp = kh ? V1t : V0t;
        for (int mt = 0; mt < 4; ++mt) {
            int rowbase = m0 + wm + mt * 16 + quad * 4;
            for (int nt = 0; nt < 4; ++nt) {
                int col = n0 + wn + nt * 16 + lane15;
                short4v pk;
                pk.x = bfs(acc[mt][nt][0]);
                pk.y = bfs(acc[mt][nt][1]);
                pk.z = bfs(acc[mt][nt][2]);
                pk.w = bfs(acc[mt][nt][3]);
                *(short4v*)((short*)Vp + (size_t)col * S_LEN + rowbase) = pk;
            }
        }
    }
}

// ---------------- reduce partials: Q,K with RoPE; V plain (already transposed) ----------------
// grid (2048, 3), 256 threads, 8 elems/thread. In-place into the half-0 buffer.
__global__ __launch_bounds__(256) void reduce_rope(__hip_bfloat16* __restrict__ Q0,
                                                   const __hip_bfloat16* __restrict__ Q1,
                                                   __hip_bfloat16* __restrict__ K0,
                                                   const __hip_bfloat16* __restrict__ K1,
                                                   __hip_bfloat16* __restrict__ V0,
                                                   const __hip_bfloat16* __restrict__ V1,
                                                   const float* __restrict__ fc,
                                                   const float* __restrict__ fs) {
    const int z = blockIdx.z;
    __hip_bfloat16* P0 = (z == 0) ? Q0 : (z == 1) ? K0 : V0;
    const __hip_bfloat16* P1 = (z == 0) ? Q1 : (z == 1) ? K1 : V1;
    size_t i0 = ((size_t)blockIdx.x * 256 + threadIdx.x) * 8;
    short8 a = *(const short8*)((const short*)P0 + i0);
    short8 b = *(const short8*)((const short*)P1 + i0);
    float s[8];
    for (int i = 0; i < 8; ++i) s[i] = sbf(((short*)&a)[i]) + sbf(((short*)&b)[i]);
    short8 o;
    if (z < 2) {
        int row = (int)(i0 >> 11);
        int col = (int)(i0 & 2047);
        int j0 = (col & 127) >> 1;
        for (int p = 0; p < 4; ++p) {
            float c = fc[row * 64 + j0 + p];
            float sn = fs[row * 64 + j0 + p];
            float e = s[2 * p], od = s[2 * p + 1];
            ((short*)&o)[2 * p]     = bfs(e * c - od * sn);
            ((short*)&o)[2 * p + 1] = bfs(e * sn + od * c);
        }
    } else {
        for (int i = 0; i < 8; ++i) ((short*)&o)[i] = bfs(s[i]);
    }
    *(short8*)((short*)P0 + i0) = o;
}

// ---------------- fallback fused QKV GEMM (RoPE epilogue, K-pair staging) ----------------
__global__ __launch_bounds__(256) void gemm_qkv_fused(const __hip_bfloat16* __restrict__ A,
                                                      const __hip_bfloat16* __restrict__ Bq,
                                                      const __hip_bfloat16* __restrict__ Bk,
                                                      const __hip_bfloat16* __restrict__ Bv,
                                                      __hip_bfloat16* __restrict__ Cq,
                                                      __hip_bfloat16* __restrict__ Ck,
                                                      __hip_bfloat16* __restrict__ Cvt,
                                                      const float* __restrict__ fc,
                                                      const float* __restrict__ fs) {
    __shared__ alignas(16) __hip_bfloat16 As[2][128 * 32];
    __shared__ alignas(16) __hip_bfloat16 Bs[2][128 * 32];
    const int which = blockIdx.x >> 4;
    const __hip_bfloat16* Bt = (which == 0) ? Bq : (which == 1) ? Bk : Bv;
    const int tid = threadIdx.x;
    const int wave = tid >> 6;
    const int lane = tid & 63;
    const int lane15 = lane & 15;
    const int quad = lane >> 4;
    const int m0 = blockIdx.y * 128;
    const int n0 = (blockIdx.x & 15) * 128;
    const int wm = (wave >> 1) * 64;
    const int wn = (wave & 1) * 64;
    f32x4 acc[4][4];
    for (int i = 0; i < 4; ++i)
        for (int j = 0; j < 4; ++j)
            acc[i][j] = {0.f, 0.f, 0.f, 0.f};
    const int rA = lane >> 2;
    const int cA = (lane & 3) * 8;
    for (int k0 = 0; k0 < DMODEL; k0 += 64) {
        __syncthreads();
        for (int h = 0; h < 2; ++h) {
            int kk = k0 + h * 32;
            for (int c = 0; c < 4; ++c) {
                int chunk = wave * 4 + c;
                if (chunk < 8) {
                    int r = chunk * 16 + rA;
                    stage16(A + (size_t)(m0 + r) * DMODEL + kk + cA, As[h] + chunk * 512, lane);
                } else {
                    int r = (chunk - 8) * 16 + rA;
                    stage16(Bt + (size_t)(n0 + r) * DMODEL + kk + cA, Bs[h] + (chunk - 8) * 512, lane);
                }
            }
        }
#if HAVE_ASYNC_LDS
        asm volatile("s_waitcnt vmcnt(0)" ::: "memory");
#endif
        __syncthreads();
        for (int h = 0; h < 2; ++h) {
            short8 af[4], bfr[4];
            for (int mt = 0; mt < 4; ++mt)
                af[mt] = *(const short8*)(As[h] + (wm + mt * 16 + lane15) * 32 + quad * 8);
            for (int nt = 0; nt < 4; ++nt)
                bfr[nt] = *(const short8*)(Bs[h] + (wn + nt * 16 + lane15) * 32 + quad * 8);
            for (int mt = 0; mt < 4; ++mt)
                for (int nt = 0; nt < 4; ++nt)
                    acc[mt][nt] = __builtin_amdgcn_mfma_f32_16x16x32_bf16(af[mt], bfr[nt], acc[mt][nt], 0, 0, 0);
        }
    }
    if (which < 2) {
        __hip_bfloat16* C = (which == 0) ? Cq : Ck;
        for (int mt = 0; mt < 4; ++mt)
            for (int nt = 0; nt < 4; ++nt) {
                int col = n0 + wn + nt * 16 + lane15;
                int j = (col & 127) >> 1;
                bool odd = col & 1;
                for (int i = 0; i < 4; ++i) {
                    int row = m0 + wm + mt * 16 + quad * 4 + i;
                    float v = acc[mt][nt][i];
                    float p = __shfl_xor(v, 1, 64);
                    float c = fc[row * 64 + j];
                    float sn = fs[row * 64 + j];
                    float r = odd ? (p * sn + v * c) : (v * c - p * sn);
                    C[(size_t)row * DMODEL + col] = f2bf(r);
                }
            }
    } else {
        for (int mt = 0; mt < 4; ++mt) {
            int rowbase = m0 + wm + mt * 16 + quad * 4;
            for (int nt = 0; nt < 4; ++nt) {
                int col = n0 + wn + nt * 16 + lane15;
                short4v pk;
                pk.x = bfs(acc[mt][nt][0]);
                pk.y = bfs(acc[mt][nt][1]);
                pk.z = bfs(acc[mt][nt][2]);
                pk.w = bfs(acc[mt][nt][3]);
                *(short4v*)((short*)Cvt + (size_t)col * S_LEN + rowbase) = pk;
            }
        }
    }
}

// ---------------- final GEMM: out(f32) = A * Bt^T, 128x64 tiles, K-pair staging ----------------
__global__ __launch_bounds__(256) void gemm_out(const __hip_bfloat16* __restrict__ A,
                                                const __hip_bfloat16* __restrict__ Bt,
                                                float* __restrict__ C) {
    __shared__ alignas(16) __hip_bfloat16 As[2][128 * 32];
    __shared__ alignas(16) __hip_bfloat16 Bs[2][64 * 32];
    const int tid = threadIdx.x;
    const int wave = tid >> 6;
    const int lane = tid & 63;
    const int lane15 = lane & 15;
    const int quad = lane >> 4;
    const int m0 = blockIdx.y * 128;
    const int n0 = blockIdx.x * 64;
    const int wm = (wave >> 1) * 64;
    const int wn = (wave & 1) * 32;
    f32x4 acc[4][2];
    for (int i = 0; i < 4; ++i)
        for (int j = 0; j < 2; ++j)
            acc[i][j] = {0.f, 0.f, 0.f, 0.f};
    const int rA = lane >> 2;
    const int cA = (lane & 3) * 8;
    for (int k0 = 0; k0 < DMODEL; k0 += 64) {
        __syncthreads();
        for (int h = 0; h < 2; ++h) {
            int kk = k0 + h * 32;
            for (int c = 0; c < 3; ++c) {
                int chunk = wave * 3 + c;
                if (chunk < 8) {
                    int r = chunk * 16 + rA;
                    stage16(A + (size_t)(m0 + r) * DMODEL + kk + cA, As[h] + chunk * 512, lane);
                } else {
                    int r = (chunk - 8) * 16 + rA;
                    stage16(Bt + (size_t)(n0 + r) * DMODEL + kk + cA, Bs[h] + (chunk - 8) * 512, lane);
                }
            }
        }
#if HAVE_ASYNC_LDS
        asm volatile("s_waitcnt vmcnt(0)" ::: "memory");
#endif
        __syncthreads();
        for (int h = 0; h < 2; ++h) {
            short8 af[4], bfr[2];
            for (int mt = 0; mt < 4; ++mt)
                af[mt] = *(const short8*)(As[h] + (wm + mt * 16 + lane15) * 32 + quad * 8);
            for (int nt = 0; nt < 2; ++nt)
                bfr[nt] = *(const short8*)(Bs[h] + (wn + nt * 16 + lane15) * 32 + quad * 8);
            for (int mt = 0; mt < 4; ++mt)
                for (int nt = 0; nt < 2; ++nt)
                    acc[mt][nt] = __builtin_amdgcn_mfma_f32_16x16x32_bf16(af[mt], bfr[nt], acc[mt][nt], 0, 0, 0);
        }
    }
    for (int mt = 0; mt < 4; ++mt)
        for (int nt = 0; nt < 2; ++nt)
            for (int i = 0; i < 4; ++i) {
                int row = m0 + wm + mt * 16 + quad * 4 + i;
                int col = n0 + wn + nt * 16 + lane15;
                C[(size_t)row * DMODEL + col] = acc[mt][nt][i];
            }
}

// ---------------- flash attention (LDS-shared K/V, fixed-base softmax) ----------------
__global__ __launch_bounds__(256) void flash_attn(const __hip_bfloat16* __restrict__ Q,
                                                  const __hip_bfloat16* __restrict__ Kb,
                                                  const __hip_bfloat16* __restrict__ Vt,
                                                  __hip_bfloat16* __restrict__ O) {
    __shared__ alignas(16) short Ks[32][136];
    __shared__ alignas(16) short Vs[128][40];
    __shared__ alignas(16) short Pl[4][16][40];
    const int tid = threadIdx.x;
    const int wave = tid >> 6;
    const int lane = tid & 63;
    const int lane15 = lane & 15;
    const int quad = lane >> 4;
    const int bx = blockIdx.x;                   // 0..511
    const int u = bx & 255;
    const int head = u & 15;
    const int qp = u >> 4;
    const int qb = (bx < 256) ? (31 - qp) : qp;  // complementary pairing
    const int qbase = qb * 64;
    const int q0w = qbase + wave * 16;
    const int nkt = 2 * qb + 2;
    const float K1 = 0.08838834764831845f * (1.0f / 25.0f);

    const __hip_bfloat16* Qh = Q + (size_t)q0w * DMODEL + head * HEAD_DIM;
    short8 qf[4];
    for (int kk = 0; kk < 4; ++kk)
        qf[kk] = *(const short8*)(Qh + (size_t)lane15 * DMODEL + kk * 32 + quad * 8);

    f32x4 acc[8];
    for (int i = 0; i < 8; ++i) acc[i] = {0.f, 0.f, 0.f, 0.f};
    float lpart[4] = {0.f, 0.f, 0.f, 0.f};

    const int krow = tid >> 3, kcol = (tid & 7) * 16;
    const int vrow = tid >> 1, vcol = (tid & 1) * 16;
    const __hip_bfloat16* Kg = Kb + (size_t)krow * DMODEL + head * HEAD_DIM + kcol;
    const __hip_bfloat16* Vg = Vt + (size_t)(head * HEAD_DIM + vrow) * S_LEN + vcol;

    short8 gk0 = *(const short8*)(Kg);
    short8 gk1 = *(const short8*)(Kg + 8);
    short8 gv0 = *(const short8*)(Vg);
    short8 gv1 = *(const short8*)(Vg + 8);

    for (int kt = 0; kt < nkt; ++kt) {
        const int kb = kt * 32;
        __syncthreads();
        *(short8*)&Ks[krow][kcol] = gk0;
        *(short8*)&Ks[krow][kcol + 8] = gk1;
        *(short8*)&Vs[vrow][vcol] = gv0;
        *(short8*)&Vs[vrow][vcol + 8] = gv1;
        __syncthreads();

        if (kt + 1 < nkt) {
            const __hip_bfloat16* Kg2 = Kg + (size_t)(kb + 32) * DMODEL;
            const __hip_bfloat16* Vg2 = Vg + kb + 32;
            gk0 = *(const short8*)(Kg2);
            gk1 = *(const short8*)(Kg2 + 8);
            gv0 = *(const short8*)(Vg2);
            gv1 = *(const short8*)(Vg2 + 8);
        }

        if (kb <= q0w + 15) {
            f32x4 sc[2];
            sc[0] = {0.f, 0.f, 0.f, 0.f};
            sc[1] = {0.f, 0.f, 0.f, 0.f};
            for (int c = 0; c < 2; ++c)
                for (int kk = 0; kk < 4; ++kk) {
                    short8 kf = *(const short8*)&Ks[c * 16 + lane15][kk * 32 + quad * 8];
                    sc[c] = __builtin_amdgcn_mfma_f32_16x16x32_bf16(qf[kk], kf, sc[c], 0, 0, 0);
                }

            const bool masked = (kb + 31 > q0w);
            const int key0 = kb + lane15;
            const int key1 = kb + 16 + lane15;
            for (int i = 0; i < 4; ++i) {
                float e0 = __expf(sc[0][i] * K1);
                float e1 = __expf(sc[1][i] * K1);
                float c0 = __builtin_fmaf(-100.0f, __builtin_amdgcn_rcpf(e0 + 1.0f), 40.0f);
                float c1 = __builtin_fmaf(-100.0f, __builtin_amdgcn_rcpf(e1 + 1.0f), 40.0f);
                float p0 = __expf(c0);
                float p1 = __expf(c1);
                if (masked) {
                    int q = q0w + quad * 4 + i;
                    if (key0 > q) p0 = 0.f;
                    if (key1 > q) p1 = 0.f;
                }
                short b0 = bfs(p0), b1 = bfs(p1);
                lpart[i] += sbf(b0) + sbf(b1);
                Pl[wave][quad * 4 + i][lane15] = b0;
                Pl[wave][quad * 4 + i][16 + lane15] = b1;
            }
            asm volatile("s_waitcnt lgkmcnt(0)" ::: "memory");
            short8 pf = *(const short8*)&Pl[wave][lane15][quad * 8];
            asm volatile("" ::: "memory");
            for (int nt = 0; nt < 8; ++nt) {
                short8 vf = *(const short8*)&Vs[nt * 16 + lane15][quad * 8];
                acc[nt] = __builtin_amdgcn_mfma_f32_16x16x32_bf16(pf, vf, acc[nt], 0, 0, 0);
            }
        }
    }

    for (int i = 0; i < 4; ++i) {
        float l = lpart[i];
        l += __shfl_xor(l, 1, 64);
        l += __shfl_xor(l, 2, 64);
        l += __shfl_xor(l, 4, 64);
        l += __shfl_xor(l, 8, 64);
        float inv = 1.0f / l;
        int row = q0w + quad * 4 + i;
        for (int nt = 0; nt < 8; ++nt) {
            int col = head * HEAD_DIM + nt * 16 + lane15;
            O[(size_t)row * DMODEL + col] = f2bf(acc[nt][i] * inv);
        }
    }
}

extern "C" void kernel_launch(void* const* d_in, const int* in_sizes, int n_in,
                              void* d_out, int out_size, void* d_ws, size_t ws_size,
                              hipStream_t stream) {
    const float* x  = (const float*)d_in[0];
    const float* wq = (const float*)d_in[1];
    const float* wk = (const float*)d_in[2];
    const float* wv = (const float*)d_in[3];
    const float* wo = (const float*)d_in[4];
    const float* fc = (const float*)d_in[5];
    const float* fs = (const float*)d_in[6];
    float* out = (float*)d_out;

    char* ws = (char*)d_ws;
    const size_t MB8 = (size_t)2048 * 2048 * sizeof(__hip_bfloat16);
    __hip_bfloat16* wq_t = (__hip_bfloat16*)(ws + 0 * MB8);
    __hip_bfloat16* wk_t = (__hip_bfloat16*)(ws + 1 * MB8);
    __hip_bfloat16* wv_t = (__hip_bfloat16*)(ws + 2 * MB8);
    __hip_bfloat16* wo_t = (__hip_bfloat16*)(ws + 3 * MB8);
    __hip_bfloat16* s4   = (__hip_bfloat16*)(ws + 4 * MB8);
    __hip_bfloat16* s5   = (__hip_bfloat16*)(ws + 5 * MB8);
    __hip_bfloat16* s6   = (__hip_bfloat16*)(ws + 6 * MB8);
    __hip_bfloat16* s7   = (__hip_bfloat16*)(ws + 7 * MB8);
    __hip_bfloat16* s8   = (__hip_bfloat16*)(ws + 8 * MB8);
    __hip_bfloat16* s9   = (__hip_bfloat16*)(ws + 9 * MB8);
    __hip_bfloat16* x_bf = (__hip_bfloat16*)d_out;  // dead before final GEMM writes d_out

    prep<<<dim3(32, 32, 5), 256, 0, stream>>>(x, wq, wk, wv, wo, x_bf, wq_t, wk_t, wv_t, wo_t);

    if (ws_size >= 10 * MB8) {
        // split-K path: partials Q0=s4 Q1=s7 K0=s5 K1=s8 V0t=s6 V1t=s9
        gemm_qkv_sk<<<dim3(96, 16), 256, 0, stream>>>(x_bf, wq_t, wk_t, wv_t,
                                                      s4, s7, s5, s8, s6, s9);
        reduce_rope<<<dim3(2048, 1, 3), 256, 0, stream>>>(s4, s7, s5, s8, s6, s9, fc, fs);
        // Qf=s4, Kf=s5, Vt=s6; attn -> s0 (wq_t dead)
        flash_attn<<<512, 256, 0, stream>>>(s4, s5, s6, wq_t);
        gemm_out<<<dim3(32, 16), 256, 0, stream>>>(wq_t, wo_t, out);
    } else {
        // fallback (7-slot) path: Qb=s4 Kbuf=s5 Vt=s6, attn -> wq_t
        gemm_qkv_fused<<<dim3(48, 16), 256, 0, stream>>>(x_bf, wq_t, wk_t, wv_t,
                                                         s4, s5, s6, fc, fs);
        flash_attn<<<512, 256, 0, stream>>>(s4, s5, s6, wq_t);
        gemm_out<<<dim3(32, 16), 256, 0, stream>>>(wq_t, wo_t, out);
    }
}